// Round 2
// baseline (2374.613 us; speedup 1.0000x reference)
//
#include <hip/hip_runtime.h>
#include <hip/hip_bf16.h>

// Problem constants
#define Bq   64
#define Tt   512
#define DIN  512
#define Ss   8
#define HSs  128
#define Hh   8
#define Mm   1024
#define KDd  128
#define NGg  2048

// ---------------------------------------------------------------------------
// Generic fp32 tiled GEMM: C[z] = A[z] @ B[z] + bias[z], optional ReLU.
// Row-major. lda/ldb/ldc are row strides (elements). sA/sB/sBias/sC are
// per-batch (blockIdx.z) offsets. Dims must divide tile sizes (all our calls do).
// ---------------------------------------------------------------------------
template<int BM, int BN, int BK, int TM, int TN, bool RELU>
__global__ __launch_bounds__(256)
void gemm_f32(const float* __restrict__ A, int lda, long long sA,
              const float* __restrict__ B, int ldb, long long sB,
              const float* __restrict__ bias, long long sBias,
              float* __restrict__ C, int ldc, long long sC,
              int Kdim)
{
    constexpr int TX = BN / TN;            // threads along N
    constexpr int TY = BM / TM;            // threads along M
    static_assert(TX * TY == 256, "256 threads");
    constexpr int KC4   = BK / 4;          // float4 per A-row of tile
    constexpr int A_PER = (BM * BK / 4) / 256;
    constexpr int B_PER = (BK * BN / 4) / 256;

    __shared__ float As[BK][BM + 4];       // transposed A tile (pad to break conflicts)
    __shared__ float Bs[BK][BN];

    const int tid = threadIdx.x;
    const int tx  = tid % TX;
    const int ty  = tid / TX;
    const long long z = blockIdx.z;
    A += z * sA;  B += z * sB;  C += z * sC;
    const float* bptr = bias + z * sBias;
    const int row0 = blockIdx.y * BM;
    const int col0 = blockIdx.x * BN;

    float acc[TM][TN];
#pragma unroll
    for (int i = 0; i < TM; ++i)
#pragma unroll
        for (int j = 0; j < TN; ++j) acc[i][j] = 0.f;

    for (int k0 = 0; k0 < Kdim; k0 += BK) {
        __syncthreads();
        // ---- load A tile (transposed into LDS) ----
#pragma unroll
        for (int l = 0; l < A_PER; ++l) {
            int idx = tid + l * 256;                 // float4 index
            int ar  = idx / KC4;                     // row in tile
            int ac  = (idx % KC4) * 4;               // k in tile
            float4 va = *(const float4*)&A[(long long)(row0 + ar) * lda + k0 + ac];
            As[ac + 0][ar] = va.x;
            As[ac + 1][ar] = va.y;
            As[ac + 2][ar] = va.z;
            As[ac + 3][ar] = va.w;
        }
        // ---- load B tile ----
#pragma unroll
        for (int l = 0; l < B_PER; ++l) {
            int idx = tid + l * 256;
            int br  = idx / (BN / 4);
            int bc  = (idx % (BN / 4)) * 4;
            *(float4*)&Bs[br][bc] = *(const float4*)&B[(long long)(k0 + br) * ldb + col0 + bc];
        }
        __syncthreads();
        // ---- compute ----
#pragma unroll
        for (int k = 0; k < BK; ++k) {
            float a[TM], b[TN];
#pragma unroll
            for (int i = 0; i < TM; i += 4)
                *(float4*)&a[i] = *(const float4*)&As[k][ty * TM + i];
#pragma unroll
            for (int j = 0; j < TN; j += 4)
                *(float4*)&b[j] = *(const float4*)&Bs[k][tx * TN + j];
#pragma unroll
            for (int i = 0; i < TM; ++i)
#pragma unroll
                for (int j = 0; j < TN; ++j)
                    acc[i][j] = fmaf(a[i], b[j], acc[i][j]);
        }
    }

    // ---- epilogue: bias (+ReLU) and store ----
#pragma unroll
    for (int i = 0; i < TM; ++i) {
        const long long crow = (long long)(row0 + ty * TM + i) * ldc;
#pragma unroll
        for (int j = 0; j < TN; j += 4) {
            const int c = col0 + tx * TN + j;
            float4 bv = *(const float4*)&bptr[c];
            float4 o;
            o.x = acc[i][j + 0] + bv.x;
            o.y = acc[i][j + 1] + bv.y;
            o.z = acc[i][j + 2] + bv.z;
            o.w = acc[i][j + 3] + bv.w;
            if (RELU) {
                o.x = fmaxf(o.x, 0.f); o.y = fmaxf(o.y, 0.f);
                o.z = fmaxf(o.z, 0.f); o.w = fmaxf(o.w, 0.f);
            }
            *(float4*)&C[crow + c] = o;
        }
    }
}

// ---------------------------------------------------------------------------
// gi_mean[b, m] = (1/T) * sum_t relu(rl_w[m] * x[b, t, m])
// x is chunk-local [Bc,T,M]; gi_mean pointer pre-offset to chunk start.
// grid: Bc * (M/256) blocks of 256 threads
// ---------------------------------------------------------------------------
__global__ __launch_bounds__(256)
void gi_reduce(const float* __restrict__ x, const float* __restrict__ rl_w,
               float* __restrict__ gi_mean)
{
    const int b    = blockIdx.x / (Mm / 256);
    const int mblk = blockIdx.x % (Mm / 256);
    const int m    = mblk * 256 + threadIdx.x;
    const float w  = rl_w[m];
    const float* xp = x + (size_t)b * Tt * Mm + m;
    float sum = 0.f;
    for (int t = 0; t < Tt; ++t)
        sum += fmaxf(w * xp[(size_t)t * Mm], 0.f);
    gi_mean[b * Mm + m] = sum * (1.f / (float)Tt);
}

// ---------------------------------------------------------------------------
// Fused attention per (b, h): scores = softmax(q k^T), att = scores @ v
// q/att pointers pre-offset to chunk start; k,v chunk-local [Bc,T,M].
// q: [.,S,M] layout (col = h*KD + d); k,v: [.,T,M] layout. No 1/sqrt(d) scale.
// ---------------------------------------------------------------------------
__global__ __launch_bounds__(256)
void attn_kernel(const float* __restrict__ q, const float* __restrict__ k,
                 const float* __restrict__ v, float* __restrict__ att)
{
    const int b = blockIdx.x / Hh;
    const int h = blockIdx.x % Hh;
    const int tid = threadIdx.x;

    __shared__ float qs[Ss][KDd];     // 4 KB
    __shared__ float sc[Ss][Tt];      // 16 KB

    // load q tile: 8 x 128 floats
    {
        int s  = tid / 32;
        int d4 = (tid % 32) * 4;
        float4 qv = *(const float4*)&q[((size_t)(b * Ss + s)) * Mm + h * KDd + d4];
        qs[s][d4 + 0] = qv.x; qs[s][d4 + 1] = qv.y;
        qs[s][d4 + 2] = qv.z; qs[s][d4 + 3] = qv.w;
    }
    __syncthreads();

    // scores: each thread computes column t for all 8 rows; two halves
#pragma unroll
    for (int half = 0; half < 2; ++half) {
        const int t = tid + half * 256;
        const float* kr = &k[((size_t)(b * Tt + t)) * Mm + h * KDd];
        float acc[Ss];
#pragma unroll
        for (int s = 0; s < Ss; ++s) acc[s] = 0.f;
        for (int d = 0; d < KDd; d += 4) {
            float4 kv = *(const float4*)(kr + d);
#pragma unroll
            for (int s = 0; s < Ss; ++s)
                acc[s] += qs[s][d + 0] * kv.x + qs[s][d + 1] * kv.y
                        + qs[s][d + 2] * kv.z + qs[s][d + 3] * kv.w;
        }
#pragma unroll
        for (int s = 0; s < Ss; ++s) sc[s][t] = acc[s];
    }
    __syncthreads();

    // softmax: 8 groups of 32 lanes, one row each
    const int s    = tid >> 5;
    const int lane = tid & 31;
    float mx = -1e30f;
    for (int t = lane; t < Tt; t += 32) mx = fmaxf(mx, sc[s][t]);
#pragma unroll
    for (int m = 16; m >= 1; m >>= 1) mx = fmaxf(mx, __shfl_xor(mx, m));
    float sum = 0.f;
    for (int t = lane; t < Tt; t += 32) {
        float e = __expf(sc[s][t] - mx);
        sc[s][t] = e;
        sum += e;
    }
#pragma unroll
    for (int m = 16; m >= 1; m >>= 1) sum += __shfl_xor(sum, m);
    const float inv = 1.f / sum;
    __syncthreads();

    // PV: thread computes att[s, d0..d0+3]
    const int d0 = (tid & 31) * 4;
    const float* vb = &v[((size_t)(b * Tt)) * Mm + h * KDd + d0];
    float4 acc = make_float4(0.f, 0.f, 0.f, 0.f);
    for (int t = 0; t < Tt; ++t) {
        const float p = sc[s][t];
        float4 vv = *(const float4*)(vb + (size_t)t * Mm);
        acc.x = fmaf(p, vv.x, acc.x);
        acc.y = fmaf(p, vv.y, acc.y);
        acc.z = fmaf(p, vv.z, acc.z);
        acc.w = fmaf(p, vv.w, acc.w);
    }
    float4 o = make_float4(acc.x * inv, acc.y * inv, acc.z * inv, acc.w * inv);
    *(float4*)&att[((size_t)(b * Ss + s)) * Mm + h * KDd + d0] = o;
}

// ---------------------------------------------------------------------------
// out = LayerNorm(a + b) * g + be   (rows of 1024)
// ---------------------------------------------------------------------------
__global__ __launch_bounds__(256)
void ln_add(const float* __restrict__ a, const float* __restrict__ b,
            const float* __restrict__ g, const float* __restrict__ be,
            float* __restrict__ out)
{
    const int row = blockIdx.x;
    const int tid = threadIdx.x;
    const float* ap = a + (size_t)row * Mm;
    const float* bp = b + (size_t)row * Mm;

    float4 av = *(const float4*)&ap[tid * 4];
    float4 bv = *(const float4*)&bp[tid * 4];
    float x0 = av.x + bv.x, x1 = av.y + bv.y, x2 = av.z + bv.z, x3 = av.w + bv.w;
    float s  = x0 + x1 + x2 + x3;
    float ss = x0 * x0 + x1 * x1 + x2 * x2 + x3 * x3;
#pragma unroll
    for (int m = 32; m >= 1; m >>= 1) {
        s  += __shfl_xor(s, m);
        ss += __shfl_xor(ss, m);
    }
    __shared__ float red[2][4];
    const int wid = tid >> 6;
    if ((tid & 63) == 0) { red[0][wid] = s; red[1][wid] = ss; }
    __syncthreads();
    s  = red[0][0] + red[0][1] + red[0][2] + red[0][3];
    ss = red[1][0] + red[1][1] + red[1][2] + red[1][3];
    const float mu  = s * (1.f / (float)Mm);
    const float var = ss * (1.f / (float)Mm) - mu * mu;
    const float inv = rsqrtf(var + 1e-5f);

    float4 gv = *(const float4*)&g[tid * 4];
    float4 bev = *(const float4*)&be[tid * 4];
    float4 o;
    o.x = (x0 - mu) * inv * gv.x + bev.x;
    o.y = (x1 - mu) * inv * gv.y + bev.y;
    o.z = (x2 - mu) * inv * gv.z + bev.z;
    o.w = (x3 - mu) * inv * gv.w + bev.w;
    *(float4*)&out[(size_t)row * Mm + tid * 4] = o;
}

__global__ __launch_bounds__(256)
void tanh_kernel(const float* __restrict__ in, float* __restrict__ out)
{
    const int idx = blockIdx.x * 256 + threadIdx.x;
    out[idx] = tanhf(in[idx]);
}

// ---------------------------------------------------------------------------
// out = sigmoid(gm_i + gi_i + ib) * tanh(next) + sigmoid(gm_f + gi_f + fb) * memory
// ---------------------------------------------------------------------------
__global__ __launch_bounds__(256)
void combine_kernel(const float* __restrict__ gm, const float* __restrict__ gi,
                    const float* __restrict__ nextm, const float* __restrict__ memory,
                    const float* __restrict__ ibp, const float* __restrict__ fbp,
                    float* __restrict__ out)
{
    const int idx = blockIdx.x * 256 + threadIdx.x;   // over B*S*M
    const int m  = idx & (Mm - 1);
    const int bs = idx >> 10;
    const int b  = bs >> 3;
    const float ib = ibp[0], fb = fbp[0];
    const float gmi = gm[(size_t)bs * NGg + m];
    const float gmf = gm[(size_t)bs * NGg + Mm + m];
    const float gii = gi[(size_t)b * NGg + m];
    const float gif = gi[(size_t)b * NGg + Mm + m];
    const float ig = 1.f / (1.f + __expf(-(gmi + gii + ib)));
    const float fg = 1.f / (1.f + __expf(-(gmf + gif + fb)));
    out[idx] = ig * tanhf(nextm[idx]) + fg * memory[idx];
}

// ---------------------------------------------------------------------------
extern "C" void kernel_launch(void* const* d_in, const int* in_sizes, int n_in,
                              void* d_out, int out_size, void* d_ws, size_t ws_size,
                              hipStream_t stream)
{
    const float* inputs = (const float*)d_in[0];
    const float* memory = (const float*)d_in[1];
    const float* Wp  = (const float*)d_in[2];
    const float* bp  = (const float*)d_in[3];
    const float* Wq  = (const float*)d_in[4];
    const float* bq  = (const float*)d_in[5];
    const float* Wk  = (const float*)d_in[6];
    const float* bk  = (const float*)d_in[7];
    const float* Wv  = (const float*)d_in[8];
    const float* bv  = (const float*)d_in[9];
    const float* Wm  = (const float*)d_in[10];
    const float* bm  = (const float*)d_in[11];
    const float* g1  = (const float*)d_in[12];
    const float* be1 = (const float*)d_in[13];
    const float* g2  = (const float*)d_in[14];
    const float* be2 = (const float*)d_in[15];
    const float* rl_w = (const float*)d_in[16];
    const float* rl_W = (const float*)d_in[17];
    const float* rl_b = (const float*)d_in[18];
    const float* gl_W = (const float*)d_in[19];
    const float* gl_b = (const float*)d_in[20];
    const float* ibp  = (const float*)d_in[21];
    const float* fbp  = (const float*)d_in[22];
    float* out = (float*)d_out;

    // ---- workspace layout: small full-B buffers first, then chunked x/k/v ----
    const size_t N_SM = (size_t)Bq * Ss * Mm;     // 524,288
    float* ws = (float*)d_ws;
    float* qbuf   = ws;
    float* attb   = qbuf   + N_SM;
    float* mem1   = attb   + N_SM;
    float* mlp1   = mem1   + N_SM;
    float* mlp2   = mlp1   + N_SM;
    float* nextm  = mlp2   + N_SM;
    float* tm     = nextm  + N_SM;
    float* gimean = tm     + N_SM;
    float* gibuf  = gimean + (size_t)Bq * Mm;
    float* gmbuf  = gibuf  + (size_t)Bq * NGg;
    float* chunk0 = gmbuf  + (size_t)Bq * Ss * NGg;
    const size_t small_floats = (size_t)(chunk0 - ws);   // ~4.92M floats (~19.7 MB)

    // pick largest batch chunk Bc such that x,k,v chunks fit in ws_size
    int Bc = Bq;
    while (Bc > 1 &&
           (small_floats + 3ull * (size_t)Bc * Tt * Mm) * sizeof(float) > ws_size)
        Bc >>= 1;
    const size_t N_XC = (size_t)Bc * Tt * Mm;
    float* xbuf = chunk0;
    float* kbuf = xbuf + N_XC;
    float* vbuf = kbuf + N_XC;

    const dim3 blk(256);

    // q = memory @ Wq + bq        [512,1024]@[1024,1024]  (full batch, small)
    gemm_f32<64,64,16,4,4,false><<<dim3(Mm/64, (Bq*Ss)/64, 1), blk, 0, stream>>>(
        memory, Mm, 0, Wq, Mm, 0, bq, 0, qbuf, Mm, 0, Mm);

    // ---- chunked over batches: x, k, v, gi_reduce, attention ----
    for (int c0 = 0; c0 < Bq; c0 += Bc) {
        const float* in_c = inputs + (size_t)c0 * Tt * DIN;
        const int rows = Bc * Tt;

        // x_c = inputs_c @ Wp + bp
        gemm_f32<128,128,16,8,8,false><<<dim3(Mm/128, rows/128, 1), blk, 0, stream>>>(
            in_c, DIN, 0, Wp, Mm, 0, bp, 0, xbuf, Mm, 0, DIN);

        // k_c = x_c @ Wk + bk
        gemm_f32<128,128,16,8,8,false><<<dim3(Mm/128, rows/128, 1), blk, 0, stream>>>(
            xbuf, Mm, 0, Wk, Mm, 0, bk, 0, kbuf, Mm, 0, Mm);

        // v_c = x_c @ Wv + bv
        gemm_f32<128,128,16,8,8,false><<<dim3(Mm/128, rows/128, 1), blk, 0, stream>>>(
            xbuf, Mm, 0, Wv, Mm, 0, bv, 0, vbuf, Mm, 0, Mm);

        // gi_mean_c = mean_t relu(rl_w * x_c)
        gi_reduce<<<dim3(Bc * (Mm/256)), blk, 0, stream>>>(
            xbuf, rl_w, gimean + (size_t)c0 * Mm);

        // attention for this chunk
        attn_kernel<<<dim3(Bc * Hh), blk, 0, stream>>>(
            qbuf + (size_t)c0 * Ss * Mm, kbuf, vbuf,
            attb + (size_t)c0 * Ss * Mm);
    }

    // mem1 = LN(memory + att)
    ln_add<<<dim3(Bq * Ss), blk, 0, stream>>>(memory, attb, g1, be1, mem1);

    // mlp = relu(relu(mem1 @ Wm + bm) @ Wm + bm)
    gemm_f32<64,64,16,4,4,true><<<dim3(Mm/64, (Bq*Ss)/64, 1), blk, 0, stream>>>(
        mem1, Mm, 0, Wm, Mm, 0, bm, 0, mlp1, Mm, 0, Mm);
    gemm_f32<64,64,16,4,4,true><<<dim3(Mm/64, (Bq*Ss)/64, 1), blk, 0, stream>>>(
        mlp1, Mm, 0, Wm, Mm, 0, bm, 0, mlp2, Mm, 0, Mm);

    // next = LN(mem1 + mlp2)
    ln_add<<<dim3(Bq * Ss), blk, 0, stream>>>(mem1, mlp2, g2, be2, nextm);

    // tm = tanh(memory)
    tanh_kernel<<<dim3((Bq*Ss*Mm)/256), blk, 0, stream>>>(memory, tm);

    // gm[:, s, :] = tanh(memory)[:, s, :] @ gl_W[s] + gl_b[s]   (batched over s)
    gemm_f32<64,64,16,4,4,false><<<dim3(NGg/64, Bq/64, Ss), blk, 0, stream>>>(
        tm, Ss*Mm, (long long)Mm,
        gl_W, NGg, (long long)Mm * NGg,
        gl_b, (long long)NGg,
        gmbuf, Ss*NGg, (long long)NGg,
        Mm);

    // gi = gi_mean @ rl_W + rl_b   [64,1024]@[1024,2048]
    gemm_f32<64,64,16,4,4,false><<<dim3(NGg/64, Bq/64, 1), blk, 0, stream>>>(
        gimean, Mm, 0, rl_W, NGg, 0, rl_b, 0, gibuf, NGg, 0, Mm);

    // final gates + output
    combine_kernel<<<dim3((Bq*Ss*Mm)/256), blk, 0, stream>>>(
        gmbuf, gibuf, nextm, memory, ibp, fbp, out);
}

// Round 4
// 828.201 us; speedup vs baseline: 2.8672x; 2.8672x over previous
//
#include <hip/hip_runtime.h>
#include <hip/hip_bf16.h>

// Problem constants
#define Bq   64
#define Tt   512
#define DIN  512
#define Ss   8
#define HSs  128
#define Hh   8
#define Mm   1024
#define KDd  128
#define NGg  2048

typedef __attribute__((ext_vector_type(8))) short bf16x8;
typedef __attribute__((ext_vector_type(4))) float f32x4;

__device__ __forceinline__ ushort f2b(float f) {
    union { float f; unsigned u; } v; v.f = f;
    unsigned r = v.u + 0x7fffu + ((v.u >> 16) & 1u);   // RNE
    return (ushort)(r >> 16);
}
__device__ __forceinline__ float b2f(ushort b) {
    union { unsigned u; float f; } v; v.u = ((unsigned)b) << 16;
    return v.f;
}

#define GLOAD_LDS16(g, l) __builtin_amdgcn_global_load_lds( \
    (const __attribute__((address_space(1))) void*)(g),     \
    (__attribute__((address_space(3))) void*)(l), 16, 0, 0)

// ---------------------------------------------------------------------------
// bf16 MFMA GEMM (m97-style): 128x128 tile, BK=32, 4 waves, 64x64 per wave.
// A [rows][K] bf16 row-major (k contiguous); Bt [N][K] bf16 (B transposed,
// k contiguous); bias fp32 [N]. OUT_BF16: C written as bf16, else fp32.
// ---------------------------------------------------------------------------
template<int OUT_BF16>
__global__ __launch_bounds__(256)
void gemm_mfma(const ushort* __restrict__ A, const ushort* __restrict__ Bt,
               const float* __restrict__ bias, void* __restrict__ Cout,
               int ldc, int Kdim)
{
    __shared__ __align__(16) ushort As[128 * 32];   // 8 KB
    __shared__ __align__(16) ushort Bs[128 * 32];   // 8 KB

    const int tid  = threadIdx.x;
    const int w    = tid >> 6;
    const int lane = tid & 63;
    const int row0 = blockIdx.y * 128;
    const int col0 = blockIdx.x * 128;
    const int wr   = w >> 1, wc = w & 1;

    f32x4 acc[4][4];
#pragma unroll
    for (int i = 0; i < 4; ++i)
#pragma unroll
        for (int j = 0; j < 4; ++j) acc[i][j] = (f32x4){0.f, 0.f, 0.f, 0.f};

    // staging: chunk c = is*256 + tid; row = c/4, k-quarter = (c&3)*8
    const ushort* Ag = A  + (size_t)(row0 + (tid >> 2)) * Kdim + (tid & 3) * 8;
    const ushort* Bg = Bt + (size_t)(col0 + (tid >> 2)) * Kdim + (tid & 3) * 8;

    for (int k0 = 0; k0 < Kdim; k0 += 32) {
        __syncthreads();
#pragma unroll
        for (int is = 0; is < 2; ++is)
            GLOAD_LDS16(Ag + (size_t)is * 64 * Kdim + k0,
                        (char*)As + (is * 256 + w * 64) * 16);
#pragma unroll
        for (int is = 0; is < 2; ++is)
            GLOAD_LDS16(Bg + (size_t)is * 64 * Kdim + k0,
                        (char*)Bs + (is * 256 + w * 64) * 16);
        asm volatile("s_waitcnt vmcnt(0)" ::: "memory");
        __syncthreads();

        bf16x8 a[4], b[4];
#pragma unroll
        for (int i = 0; i < 4; ++i) {
            a[i] = *(const bf16x8*)&As[(wr * 64 + i * 16 + (lane & 15)) * 32 + (lane >> 4) * 8];
            b[i] = *(const bf16x8*)&Bs[(wc * 64 + i * 16 + (lane & 15)) * 32 + (lane >> 4) * 8];
        }
#pragma unroll
        for (int i = 0; i < 4; ++i)
#pragma unroll
            for (int j = 0; j < 4; ++j)
                acc[i][j] = __builtin_amdgcn_mfma_f32_16x16x32_bf16(a[i], b[j], acc[i][j], 0, 0, 0);
    }

    // epilogue: D row = wr*64+i*16+(lane>>4)*4+r ; col = wc*64+j*16+(lane&15)
    float bsv[4];
#pragma unroll
    for (int j = 0; j < 4; ++j) bsv[j] = bias[col0 + wc * 64 + j * 16 + (lane & 15)];
#pragma unroll
    for (int i = 0; i < 4; ++i) {
        const int row = row0 + wr * 64 + i * 16 + (lane >> 4) * 4;
        const int col = col0 + wc * 64 + (lane & 15);
#pragma unroll
        for (int r = 0; r < 4; ++r) {
            const size_t off = (size_t)(row + r) * ldc + col;
#pragma unroll
            for (int j = 0; j < 4; ++j) {
                float vv = acc[i][j][r] + bsv[j];
                if (OUT_BF16) ((ushort*)Cout)[off + j * 16] = f2b(vv);
                else          ((float*)Cout)[off + j * 16]  = vv;
            }
        }
    }
}

// ---------------------------------------------------------------------------
// transpose + convert: out[C][R] bf16 = in[R][C] fp32   (R,C multiples of 32)
// ---------------------------------------------------------------------------
__global__ __launch_bounds__(256)
void transpose_to_bf16(const float* __restrict__ in, ushort* __restrict__ out,
                       int R, int C)
{
    __shared__ float t[32][33];
    const int c0 = blockIdx.x * 32, r0 = blockIdx.y * 32;
    const int tx = threadIdx.x & 31, ty = threadIdx.x >> 5;   // 32 x 8
#pragma unroll
    for (int i = 0; i < 32; i += 8)
        t[ty + i][tx] = in[(size_t)(r0 + ty + i) * C + c0 + tx];
    __syncthreads();
#pragma unroll
    for (int i = 0; i < 32; i += 8)
        out[(size_t)(c0 + ty + i) * R + r0 + tx] = f2b(t[tx][ty + i]);
}

// elementwise fp32 -> bf16 (n divisible by 1024)
__global__ __launch_bounds__(256)
void conv_bf16(const float* __restrict__ in, ushort* __restrict__ out)
{
    const int i = blockIdx.x * 256 + threadIdx.x;
    float4 v = ((const float4*)in)[i];
    ushort4 o;
    o.x = f2b(v.x); o.y = f2b(v.y); o.z = f2b(v.z); o.w = f2b(v.w);
    ((ushort4*)out)[i] = o;
}

// ---------------------------------------------------------------------------
// Generic fp32 tiled GEMM (for the small matmuls): C[z] = A[z]@B[z]+bias[z]
// ---------------------------------------------------------------------------
template<int BM, int BN, int BK, int TM, int TN, bool RELU>
__global__ __launch_bounds__(256)
void gemm_f32(const float* __restrict__ A, int lda, long long sA,
              const float* __restrict__ B, int ldb, long long sB,
              const float* __restrict__ bias, long long sBias,
              float* __restrict__ C, int ldc, long long sC,
              int Kdim)
{
    constexpr int TX = BN / TN;
    constexpr int TY = BM / TM;
    static_assert(TX * TY == 256, "256 threads");
    constexpr int KC4   = BK / 4;
    constexpr int A_PER = (BM * BK / 4) / 256;
    constexpr int B_PER = (BK * BN / 4) / 256;

    __shared__ float As[BK][BM + 4];
    __shared__ float Bs[BK][BN];

    const int tid = threadIdx.x;
    const int tx  = tid % TX;
    const int ty  = tid / TX;
    const long long z = blockIdx.z;
    A += z * sA;  B += z * sB;  C += z * sC;
    const float* bptr = bias + z * sBias;
    const int row0 = blockIdx.y * BM;
    const int col0 = blockIdx.x * BN;

    float acc[TM][TN];
#pragma unroll
    for (int i = 0; i < TM; ++i)
#pragma unroll
        for (int j = 0; j < TN; ++j) acc[i][j] = 0.f;

    for (int k0 = 0; k0 < Kdim; k0 += BK) {
        __syncthreads();
#pragma unroll
        for (int l = 0; l < A_PER; ++l) {
            int idx = tid + l * 256;
            int ar  = idx / KC4;
            int ac  = (idx % KC4) * 4;
            float4 va = *(const float4*)&A[(long long)(row0 + ar) * lda + k0 + ac];
            As[ac + 0][ar] = va.x;
            As[ac + 1][ar] = va.y;
            As[ac + 2][ar] = va.z;
            As[ac + 3][ar] = va.w;
        }
#pragma unroll
        for (int l = 0; l < B_PER; ++l) {
            int idx = tid + l * 256;
            int br  = idx / (BN / 4);
            int bc  = (idx % (BN / 4)) * 4;
            *(float4*)&Bs[br][bc] = *(const float4*)&B[(long long)(k0 + br) * ldb + col0 + bc];
        }
        __syncthreads();
#pragma unroll
        for (int k = 0; k < BK; ++k) {
            float a[TM], b[TN];
#pragma unroll
            for (int i = 0; i < TM; i += 4)
                *(float4*)&a[i] = *(const float4*)&As[k][ty * TM + i];
#pragma unroll
            for (int j = 0; j < TN; j += 4)
                *(float4*)&b[j] = *(const float4*)&Bs[k][tx * TN + j];
#pragma unroll
            for (int i = 0; i < TM; ++i)
#pragma unroll
                for (int j = 0; j < TN; ++j)
                    acc[i][j] = fmaf(a[i], b[j], acc[i][j]);
        }
    }

#pragma unroll
    for (int i = 0; i < TM; ++i) {
        const long long crow = (long long)(row0 + ty * TM + i) * ldc;
#pragma unroll
        for (int j = 0; j < TN; j += 4) {
            const int c = col0 + tx * TN + j;
            float4 bv = *(const float4*)&bptr[c];
            float4 o;
            o.x = acc[i][j + 0] + bv.x;
            o.y = acc[i][j + 1] + bv.y;
            o.z = acc[i][j + 2] + bv.z;
            o.w = acc[i][j + 3] + bv.w;
            if (RELU) {
                o.x = fmaxf(o.x, 0.f); o.y = fmaxf(o.y, 0.f);
                o.z = fmaxf(o.z, 0.f); o.w = fmaxf(o.w, 0.f);
            }
            *(float4*)&C[crow + c] = o;
        }
    }
}

// ---------------------------------------------------------------------------
// gi_mean[b, m] = (1/T) * sum_t relu(rl_w[m] * x_bf16[b, t, m])
// ---------------------------------------------------------------------------
__global__ __launch_bounds__(256)
void gi_reduce(const ushort* __restrict__ x, const float* __restrict__ rl_w,
               float* __restrict__ gi_mean)
{
    const int b    = blockIdx.x / (Mm / 256);
    const int mblk = blockIdx.x % (Mm / 256);
    const int m    = mblk * 256 + threadIdx.x;
    const float w  = rl_w[m];
    const ushort* xp = x + (size_t)b * Tt * Mm + m;
    float sum = 0.f;
    for (int t = 0; t < Tt; ++t)
        sum += fmaxf(w * b2f(xp[(size_t)t * Mm]), 0.f);
    gi_mean[b * Mm + m] = sum * (1.f / (float)Tt);
}

// ---------------------------------------------------------------------------
// Fused attention per (b, h) — fp32
// ---------------------------------------------------------------------------
__global__ __launch_bounds__(256)
void attn_kernel(const float* __restrict__ q, const float* __restrict__ k,
                 const float* __restrict__ v, float* __restrict__ att)
{
    const int b = blockIdx.x / Hh;
    const int h = blockIdx.x % Hh;
    const int tid = threadIdx.x;

    __shared__ float qs[Ss][KDd];
    __shared__ float sc[Ss][Tt];

    {
        int s  = tid / 32;
        int d4 = (tid % 32) * 4;
        float4 qv = *(const float4*)&q[((size_t)(b * Ss + s)) * Mm + h * KDd + d4];
        qs[s][d4 + 0] = qv.x; qs[s][d4 + 1] = qv.y;
        qs[s][d4 + 2] = qv.z; qs[s][d4 + 3] = qv.w;
    }
    __syncthreads();

#pragma unroll
    for (int half = 0; half < 2; ++half) {
        const int t = tid + half * 256;
        const float* kr = &k[((size_t)(b * Tt + t)) * Mm + h * KDd];
        float acc[Ss];
#pragma unroll
        for (int s = 0; s < Ss; ++s) acc[s] = 0.f;
        for (int d = 0; d < KDd; d += 4) {
            float4 kv = *(const float4*)(kr + d);
#pragma unroll
            for (int s = 0; s < Ss; ++s)
                acc[s] += qs[s][d + 0] * kv.x + qs[s][d + 1] * kv.y
                        + qs[s][d + 2] * kv.z + qs[s][d + 3] * kv.w;
        }
#pragma unroll
        for (int s = 0; s < Ss; ++s) sc[s][t] = acc[s];
    }
    __syncthreads();

    const int s    = tid >> 5;
    const int lane = tid & 31;
    float mx = -1e30f;
    for (int t = lane; t < Tt; t += 32) mx = fmaxf(mx, sc[s][t]);
#pragma unroll
    for (int m = 16; m >= 1; m >>= 1) mx = fmaxf(mx, __shfl_xor(mx, m));
    float sum = 0.f;
    for (int t = lane; t < Tt; t += 32) {
        float e = __expf(sc[s][t] - mx);
        sc[s][t] = e;
        sum += e;
    }
#pragma unroll
    for (int m = 16; m >= 1; m >>= 1) sum += __shfl_xor(sum, m);
    const float inv = 1.f / sum;
    __syncthreads();

    const int d0 = (tid & 31) * 4;
    const float* vb = &v[((size_t)(b * Tt)) * Mm + h * KDd + d0];
    float4 acc = make_float4(0.f, 0.f, 0.f, 0.f);
    for (int t = 0; t < Tt; ++t) {
        const float p = sc[s][t];
        float4 vv = *(const float4*)(vb + (size_t)t * Mm);
        acc.x = fmaf(p, vv.x, acc.x);
        acc.y = fmaf(p, vv.y, acc.y);
        acc.z = fmaf(p, vv.z, acc.z);
        acc.w = fmaf(p, vv.w, acc.w);
    }
    float4 o = make_float4(acc.x * inv, acc.y * inv, acc.z * inv, acc.w * inv);
    *(float4*)&att[((size_t)(b * Ss + s)) * Mm + h * KDd + d0] = o;
}

// ---------------------------------------------------------------------------
__global__ __launch_bounds__(256)
void ln_add(const float* __restrict__ a, const float* __restrict__ b,
            const float* __restrict__ g, const float* __restrict__ be,
            float* __restrict__ out)
{
    const int row = blockIdx.x;
    const int tid = threadIdx.x;
    const float* ap = a + (size_t)row * Mm;
    const float* bp = b + (size_t)row * Mm;

    float4 av = *(const float4*)&ap[tid * 4];
    float4 bv = *(const float4*)&bp[tid * 4];
    float x0 = av.x + bv.x, x1 = av.y + bv.y, x2 = av.z + bv.z, x3 = av.w + bv.w;
    float s  = x0 + x1 + x2 + x3;
    float ss = x0 * x0 + x1 * x1 + x2 * x2 + x3 * x3;
#pragma unroll
    for (int m = 32; m >= 1; m >>= 1) {
        s  += __shfl_xor(s, m);
        ss += __shfl_xor(ss, m);
    }
    __shared__ float red[2][4];
    const int wid = tid >> 6;
    if ((tid & 63) == 0) { red[0][wid] = s; red[1][wid] = ss; }
    __syncthreads();
    s  = red[0][0] + red[0][1] + red[0][2] + red[0][3];
    ss = red[1][0] + red[1][1] + red[1][2] + red[1][3];
    const float mu  = s * (1.f / (float)Mm);
    const float var = ss * (1.f / (float)Mm) - mu * mu;
    const float inv = rsqrtf(var + 1e-5f);

    float4 gv = *(const float4*)&g[tid * 4];
    float4 bev = *(const float4*)&be[tid * 4];
    float4 o;
    o.x = (x0 - mu) * inv * gv.x + bev.x;
    o.y = (x1 - mu) * inv * gv.y + bev.y;
    o.z = (x2 - mu) * inv * gv.z + bev.z;
    o.w = (x3 - mu) * inv * gv.w + bev.w;
    *(float4*)&out[(size_t)row * Mm + tid * 4] = o;
}

__global__ __launch_bounds__(256)
void tanh_kernel(const float* __restrict__ in, float* __restrict__ out)
{
    const int idx = blockIdx.x * 256 + threadIdx.x;
    out[idx] = tanhf(in[idx]);
}

__global__ __launch_bounds__(256)
void combine_kernel(const float* __restrict__ gm, const float* __restrict__ gi,
                    const float* __restrict__ nextm, const float* __restrict__ memory,
                    const float* __restrict__ ibp, const float* __restrict__ fbp,
                    float* __restrict__ out)
{
    const int idx = blockIdx.x * 256 + threadIdx.x;
    const int m  = idx & (Mm - 1);
    const int bs = idx >> 10;
    const int b  = bs >> 3;
    const float ib = ibp[0], fb = fbp[0];
    const float gmi = gm[(size_t)bs * NGg + m];
    const float gmf = gm[(size_t)bs * NGg + Mm + m];
    const float gii = gi[(size_t)b * NGg + m];
    const float gif = gi[(size_t)b * NGg + Mm + m];
    const float ig = 1.f / (1.f + __expf(-(gmi + gii + ib)));
    const float fg = 1.f / (1.f + __expf(-(gmf + gif + fb)));
    out[idx] = ig * tanhf(nextm[idx]) + fg * memory[idx];
}

// ---------------------------------------------------------------------------
extern "C" void kernel_launch(void* const* d_in, const int* in_sizes, int n_in,
                              void* d_out, int out_size, void* d_ws, size_t ws_size,
                              hipStream_t stream)
{
    const float* inputs = (const float*)d_in[0];
    const float* memory = (const float*)d_in[1];
    const float* Wp  = (const float*)d_in[2];
    const float* bp  = (const float*)d_in[3];
    const float* Wq  = (const float*)d_in[4];
    const float* bq  = (const float*)d_in[5];
    const float* Wk  = (const float*)d_in[6];
    const float* bk  = (const float*)d_in[7];
    const float* Wv  = (const float*)d_in[8];
    const float* bv  = (const float*)d_in[9];
    const float* Wm  = (const float*)d_in[10];
    const float* bm  = (const float*)d_in[11];
    const float* g1  = (const float*)d_in[12];
    const float* be1 = (const float*)d_in[13];
    const float* g2  = (const float*)d_in[14];
    const float* be2 = (const float*)d_in[15];
    const float* rl_w = (const float*)d_in[16];
    const float* rl_W = (const float*)d_in[17];
    const float* rl_b = (const float*)d_in[18];
    const float* gl_W = (const float*)d_in[19];
    const float* gl_b = (const float*)d_in[20];
    const float* ibp  = (const float*)d_in[21];
    const float* fbp  = (const float*)d_in[22];
    float* out = (float*)d_out;

    // ---- workspace layout (float units) ----
    const size_t N_SM = (size_t)Bq * Ss * Mm;     // 524,288
    float* ws = (float*)d_ws;
    float* qbuf   = ws;
    float* attb   = qbuf   + N_SM;
    float* mem1   = attb   + N_SM;
    float* mlp1   = mem1   + N_SM;
    float* mlp2   = mlp1   + N_SM;
    float* nextm  = mlp2   + N_SM;
    float* tm     = nextm  + N_SM;
    float* gimean = tm     + N_SM;
    float* gibuf  = gimean + (size_t)Bq * Mm;
    float* gmbuf  = gibuf  + (size_t)Bq * NGg;
    float* pconst = gmbuf  + (size_t)Bq * Ss * NGg;
    // bf16 constants (pconst is 16B-aligned: offset 19,660,800 bytes from ws)
    ushort* ib16 = (ushort*)pconst;                       // [B*T][DIN]
    ushort* WpT  = ib16 + (size_t)Bq * Tt * DIN;          // [M][DIN]
    ushort* WkT  = WpT  + (size_t)Mm * DIN;               // [M][M]
    ushort* WvT  = WkT  + (size_t)Mm * Mm;                // [M][M]
    ushort* cend = WvT  + (size_t)Mm * Mm;
    // chunk region start (float*, 16B aligned)
    size_t const_u16 = (size_t)(cend - (ushort*)pconst);
    size_t const_floats = (size_t)(pconst - ws) + (const_u16 + 1) / 2;
    const_floats = (const_floats + 3) & ~(size_t)3;       // 16B align
    float* cstart = ws + const_floats;

    // per-chunk: kbuf fp32 (Bc*T*M) + vbuf fp32 (Bc*T*M) + xb16 (Bc*T*M u16)
    int Bc = Bq;
    while (Bc > 1 &&
           (const_floats + (size_t)Bc * Tt * Mm * 5 / 2) * sizeof(float) > ws_size)
        Bc >>= 1;
    const size_t N_XC = (size_t)Bc * Tt * Mm;
    float*  kbuf = cstart;
    float*  vbuf = kbuf + N_XC;
    ushort* xb16 = (ushort*)(vbuf + N_XC);

    const dim3 blk(256);

    // ---- precompute bf16 operands ----
    conv_bf16<<<dim3((Bq * Tt * DIN) / 1024), blk, 0, stream>>>(inputs, ib16);
    transpose_to_bf16<<<dim3(Mm / 32, DIN / 32), blk, 0, stream>>>(Wp, WpT, DIN, Mm);
    transpose_to_bf16<<<dim3(Mm / 32, Mm / 32), blk, 0, stream>>>(Wk, WkT, Mm, Mm);
    transpose_to_bf16<<<dim3(Mm / 32, Mm / 32), blk, 0, stream>>>(Wv, WvT, Mm, Mm);

    // q = memory @ Wq + bq   (fp32, small)
    gemm_f32<64,64,16,4,4,false><<<dim3(Mm/64, (Bq*Ss)/64, 1), blk, 0, stream>>>(
        memory, Mm, 0, Wq, Mm, 0, bq, 0, qbuf, Mm, 0, Mm);

    // ---- chunked: x(bf16), k, v, gi_reduce, attention ----
    for (int c0 = 0; c0 < Bq; c0 += Bc) {
        const int rows = Bc * Tt;

        // x_bf16 = bf16(inputs_c @ Wp + bp)
        gemm_mfma<1><<<dim3(Mm/128, rows/128), blk, 0, stream>>>(
            ib16 + (size_t)c0 * Tt * DIN, WpT, bp, xb16, Mm, DIN);

        // k = x @ Wk + bk  (fp32 out)
        gemm_mfma<0><<<dim3(Mm/128, rows/128), blk, 0, stream>>>(
            xb16, WkT, bk, kbuf, Mm, Mm);

        // v = x @ Wv + bv
        gemm_mfma<0><<<dim3(Mm/128, rows/128), blk, 0, stream>>>(
            xb16, WvT, bv, vbuf, Mm, Mm);

        // gi_mean_c = mean_t relu(rl_w * x)
        gi_reduce<<<dim3(Bc * (Mm/256)), blk, 0, stream>>>(
            xb16, rl_w, gimean + (size_t)c0 * Mm);

        // attention for this chunk
        attn_kernel<<<dim3(Bc * Hh), blk, 0, stream>>>(
            qbuf + (size_t)c0 * Ss * Mm, kbuf, vbuf,
            attb + (size_t)c0 * Ss * Mm);
    }

    // mem1 = LN(memory + att)
    ln_add<<<dim3(Bq * Ss), blk, 0, stream>>>(memory, attb, g1, be1, mem1);

    // mlp = relu(relu(mem1 @ Wm + bm) @ Wm + bm)
    gemm_f32<64,64,16,4,4,true><<<dim3(Mm/64, (Bq*Ss)/64, 1), blk, 0, stream>>>(
        mem1, Mm, 0, Wm, Mm, 0, bm, 0, mlp1, Mm, 0, Mm);
    gemm_f32<64,64,16,4,4,true><<<dim3(Mm/64, (Bq*Ss)/64, 1), blk, 0, stream>>>(
        mlp1, Mm, 0, Wm, Mm, 0, bm, 0, mlp2, Mm, 0, Mm);

    // next = LN(mem1 + mlp2)
    ln_add<<<dim3(Bq * Ss), blk, 0, stream>>>(mem1, mlp2, g2, be2, nextm);

    // tm = tanh(memory)
    tanh_kernel<<<dim3((Bq*Ss*Mm)/256), blk, 0, stream>>>(memory, tm);

    // gm[:, s, :] = tanh(memory)[:, s, :] @ gl_W[s] + gl_b[s]
    gemm_f32<64,64,16,4,4,false><<<dim3(NGg/64, Bq/64, Ss), blk, 0, stream>>>(
        tm, Ss*Mm, (long long)Mm,
        gl_W, NGg, (long long)Mm * NGg,
        gl_b, (long long)NGg,
        gmbuf, Ss*NGg, (long long)NGg,
        Mm);

    // gi = gi_mean @ rl_W + rl_b
    gemm_f32<64,64,16,4,4,false><<<dim3(NGg/64, Bq/64, 1), blk, 0, stream>>>(
        gimean, Mm, 0, rl_W, NGg, 0, rl_b, 0, gibuf, NGg, 0, Mm);

    // final gates + output
    combine_kernel<<<dim3((Bq*Ss*Mm)/256), blk, 0, stream>>>(
        gmbuf, gibuf, nextm, memory, ibp, fbp, out);
}

// Round 5
// 627.269 us; speedup vs baseline: 3.7856x; 1.3203x over previous
//
#include <hip/hip_runtime.h>
#include <hip/hip_bf16.h>

// Problem constants
#define Bq   64
#define Tt   512
#define DIN  512
#define Ss   8
#define HSs  128
#define Hh   8
#define Mm   1024
#define KDd  128
#define NGg  2048

typedef __attribute__((ext_vector_type(8))) short bf16x8;
typedef __attribute__((ext_vector_type(4))) float f32x4;

__device__ __forceinline__ ushort f2b(float f) {
    union { float f; unsigned u; } v; v.f = f;
    unsigned r = v.u + 0x7fffu + ((v.u >> 16) & 1u);   // RNE
    return (ushort)(r >> 16);
}
__device__ __forceinline__ float b2f(ushort b) {
    union { unsigned u; float f; } v; v.u = ((unsigned)b) << 16;
    return v.f;
}

#define GLOAD_LDS16(g, l) __builtin_amdgcn_global_load_lds( \
    (const __attribute__((address_space(1))) void*)(g),     \
    (__attribute__((address_space(3))) void*)(l), 16, 0, 0)

// ---------------------------------------------------------------------------
// bf16 MFMA GEMM (m97-style): 128x128 tile, BK=32, 4 waves, 64x64 per wave.
// A [rows][K] bf16 row-major; Bt [N][K] bf16 (B transposed, k contiguous);
// bias fp32 [N]. OUT_BF16: C written as bf16, else fp32.
// ---------------------------------------------------------------------------
template<int OUT_BF16>
__global__ __launch_bounds__(256)
void gemm_mfma(const ushort* __restrict__ A, const ushort* __restrict__ Bt,
               const float* __restrict__ bias, void* __restrict__ Cout,
               int ldc, int Kdim)
{
    __shared__ __align__(16) ushort As[128 * 32];   // 8 KB
    __shared__ __align__(16) ushort Bs[128 * 32];   // 8 KB

    const int tid  = threadIdx.x;
    const int w    = tid >> 6;
    const int lane = tid & 63;
    const int row0 = blockIdx.y * 128;
    const int col0 = blockIdx.x * 128;
    const int wr   = w >> 1, wc = w & 1;

    f32x4 acc[4][4];
#pragma unroll
    for (int i = 0; i < 4; ++i)
#pragma unroll
        for (int j = 0; j < 4; ++j) acc[i][j] = (f32x4){0.f, 0.f, 0.f, 0.f};

    // staging: chunk c = is*256 + tid; row = c/4, k-quarter = (c&3)*8
    const ushort* Ag = A  + (size_t)(row0 + (tid >> 2)) * Kdim + (tid & 3) * 8;
    const ushort* Bg = Bt + (size_t)(col0 + (tid >> 2)) * Kdim + (tid & 3) * 8;

    for (int k0 = 0; k0 < Kdim; k0 += 32) {
        __syncthreads();
#pragma unroll
        for (int is = 0; is < 2; ++is)
            GLOAD_LDS16(Ag + (size_t)is * 64 * Kdim + k0,
                        (char*)As + (is * 256 + w * 64) * 16);
#pragma unroll
        for (int is = 0; is < 2; ++is)
            GLOAD_LDS16(Bg + (size_t)is * 64 * Kdim + k0,
                        (char*)Bs + (is * 256 + w * 64) * 16);
        asm volatile("s_waitcnt vmcnt(0)" ::: "memory");
        __syncthreads();

        bf16x8 a[4], b[4];
#pragma unroll
        for (int i = 0; i < 4; ++i) {
            a[i] = *(const bf16x8*)&As[(wr * 64 + i * 16 + (lane & 15)) * 32 + (lane >> 4) * 8];
            b[i] = *(const bf16x8*)&Bs[(wc * 64 + i * 16 + (lane & 15)) * 32 + (lane >> 4) * 8];
        }
#pragma unroll
        for (int i = 0; i < 4; ++i)
#pragma unroll
            for (int j = 0; j < 4; ++j)
                acc[i][j] = __builtin_amdgcn_mfma_f32_16x16x32_bf16(a[i], b[j], acc[i][j], 0, 0, 0);
    }

    // epilogue: D row = wr*64+i*16+(lane>>4)*4+r ; col = wc*64+j*16+(lane&15)
    float bsv[4];
#pragma unroll
    for (int j = 0; j < 4; ++j) bsv[j] = bias[col0 + wc * 64 + j * 16 + (lane & 15)];
#pragma unroll
    for (int i = 0; i < 4; ++i) {
        const int row = row0 + wr * 64 + i * 16 + (lane >> 4) * 4;
        const int col = col0 + wc * 64 + (lane & 15);
#pragma unroll
        for (int r = 0; r < 4; ++r) {
            const size_t off = (size_t)(row + r) * ldc + col;
#pragma unroll
            for (int j = 0; j < 4; ++j) {
                float vv = acc[i][j][r] + bsv[j];
                if (OUT_BF16) ((ushort*)Cout)[off + j * 16] = f2b(vv);
                else          ((float*)Cout)[off + j * 16]  = vv;
            }
        }
    }
}

// ---------------------------------------------------------------------------
// transpose + convert: out[C][R] bf16 = in[R][C] fp32   (R,C multiples of 32)
// ---------------------------------------------------------------------------
__global__ __launch_bounds__(256)
void transpose_to_bf16(const float* __restrict__ in, ushort* __restrict__ out,
                       int R, int C)
{
    __shared__ float t[32][33];
    const int c0 = blockIdx.x * 32, r0 = blockIdx.y * 32;
    const int tx = threadIdx.x & 31, ty = threadIdx.x >> 5;   // 32 x 8
#pragma unroll
    for (int i = 0; i < 32; i += 8)
        t[ty + i][tx] = in[(size_t)(r0 + ty + i) * C + c0 + tx];
    __syncthreads();
#pragma unroll
    for (int i = 0; i < 32; i += 8)
        out[(size_t)(c0 + ty + i) * R + r0 + tx] = f2b(t[tx][ty + i]);
}

// elementwise fp32 -> bf16 (n divisible by 1024)
__global__ __launch_bounds__(256)
void conv_bf16(const float* __restrict__ in, ushort* __restrict__ out)
{
    const int i = blockIdx.x * 256 + threadIdx.x;
    float4 v = ((const float4*)in)[i];
    ushort4 o;
    o.x = f2b(v.x); o.y = f2b(v.y); o.z = f2b(v.z); o.w = f2b(v.w);
    ((ushort4*)out)[i] = o;
}

// ---------------------------------------------------------------------------
// Split-K fp32 GEMM: partials P[zz][Mrows][Ncols], zz = batch*SPLITK + ks.
// No bias/activation here (applied in sk_reduce).
// ---------------------------------------------------------------------------
template<int BM, int BN, int BK, int TM, int TN, int SPLITK>
__global__ __launch_bounds__(256)
void gemm_f32_sk(const float* __restrict__ A, int lda, long long sA,
                 const float* __restrict__ B, int ldb, long long sB,
                 float* __restrict__ P, int Mrows, int Ncols, int Kdim)
{
    constexpr int TX = BN / TN;
    constexpr int TY = BM / TM;
    static_assert(TX * TY == 256, "256 threads");
    constexpr int KC4   = BK / 4;
    constexpr int A_PER = (BM * BK / 4) / 256;
    constexpr int B_PER = (BK * BN / 4) / 256;

    __shared__ float As[BK][BM + 4];
    __shared__ float Bs[BK][BN];

    const int tid = threadIdx.x;
    const int tx  = tid % TX;
    const int ty  = tid / TX;
    const int zz  = blockIdx.z;
    const int zb  = zz / SPLITK;
    const int ks  = zz % SPLITK;
    A += (long long)zb * sA;
    B += (long long)zb * sB;
    const int Kslice = Kdim / SPLITK;
    const int kbeg = ks * Kslice, kend = kbeg + Kslice;
    const int row0 = blockIdx.y * BM;
    const int col0 = blockIdx.x * BN;

    float acc[TM][TN];
#pragma unroll
    for (int i = 0; i < TM; ++i)
#pragma unroll
        for (int j = 0; j < TN; ++j) acc[i][j] = 0.f;

    for (int k0 = kbeg; k0 < kend; k0 += BK) {
        __syncthreads();
#pragma unroll
        for (int l = 0; l < A_PER; ++l) {
            int idx = tid + l * 256;
            int ar  = idx / KC4;
            int ac  = (idx % KC4) * 4;
            float4 va = *(const float4*)&A[(long long)(row0 + ar) * lda + k0 + ac];
            As[ac + 0][ar] = va.x;
            As[ac + 1][ar] = va.y;
            As[ac + 2][ar] = va.z;
            As[ac + 3][ar] = va.w;
        }
#pragma unroll
        for (int l = 0; l < B_PER; ++l) {
            int idx = tid + l * 256;
            int br  = idx / (BN / 4);
            int bc  = (idx % (BN / 4)) * 4;
            *(float4*)&Bs[br][bc] = *(const float4*)&B[(long long)(k0 + br) * ldb + col0 + bc];
        }
        __syncthreads();
#pragma unroll
        for (int k = 0; k < BK; ++k) {
            float a[TM], b[TN];
#pragma unroll
            for (int i = 0; i < TM; i += 4)
                *(float4*)&a[i] = *(const float4*)&As[k][ty * TM + i];
#pragma unroll
            for (int j = 0; j < TN; j += 4)
                *(float4*)&b[j] = *(const float4*)&Bs[k][tx * TN + j];
#pragma unroll
            for (int i = 0; i < TM; ++i)
#pragma unroll
                for (int j = 0; j < TN; ++j)
                    acc[i][j] = fmaf(a[i], b[j], acc[i][j]);
        }
    }

    float* Pz = P + (size_t)zz * Mrows * Ncols;
#pragma unroll
    for (int i = 0; i < TM; ++i) {
        const size_t prow = (size_t)(row0 + ty * TM + i) * Ncols;
#pragma unroll
        for (int j = 0; j < TN; j += 4)
            *(float4*)&Pz[prow + col0 + tx * TN + j] = *(const float4*)&acc[i][j];
    }
}

// ---------------------------------------------------------------------------
// sk_reduce: C[batch][row][col] = (relu?)( sum_ks P + bias[batch][col] )
// pb4 = Mrows*Ncols/4 (float4 units per partial). Grid covers Zb*pb4 threads.
// ---------------------------------------------------------------------------
template<int SPLITK, bool RELU>
__global__ __launch_bounds__(256)
void sk_reduce(const float* __restrict__ P, const float* __restrict__ bias,
               long long sBias, float* __restrict__ C, int ldc, long long sC,
               int pb4, int Ncols)
{
    const int gid = blockIdx.x * 256 + threadIdx.x;
    const int batch = gid / pb4;
    const int r4    = gid % pb4;
    const float4* Pb = (const float4*)P + (size_t)batch * SPLITK * pb4 + r4;
    float4 s = Pb[0];
#pragma unroll
    for (int ks = 1; ks < SPLITK; ++ks) {
        float4 p = Pb[(size_t)ks * pb4];
        s.x += p.x; s.y += p.y; s.z += p.z; s.w += p.w;
    }
    const int col = (r4 * 4) % Ncols;
    const int row = (r4 * 4) / Ncols;
    float4 bv = *(const float4*)&bias[batch * sBias + col];
    s.x += bv.x; s.y += bv.y; s.z += bv.z; s.w += bv.w;
    if (RELU) {
        s.x = fmaxf(s.x, 0.f); s.y = fmaxf(s.y, 0.f);
        s.z = fmaxf(s.z, 0.f); s.w = fmaxf(s.w, 0.f);
    }
    *(float4*)&C[(size_t)batch * sC + (size_t)row * ldc + col] = s;
}

// ---------------------------------------------------------------------------
// gi_mean[b, m] = (1/T) * sum_t relu(rl_w[m] * x_bf16[b, t, m])
// ---------------------------------------------------------------------------
__global__ __launch_bounds__(256)
void gi_reduce(const ushort* __restrict__ x, const float* __restrict__ rl_w,
               float* __restrict__ gi_mean)
{
    const int b    = blockIdx.x / (Mm / 256);
    const int mblk = blockIdx.x % (Mm / 256);
    const int m    = mblk * 256 + threadIdx.x;
    const float w  = rl_w[m];
    const ushort* xp = x + (size_t)b * Tt * Mm + m;
    float sum = 0.f;
    for (int t = 0; t < Tt; ++t)
        sum += fmaxf(w * b2f(xp[(size_t)t * Mm]), 0.f);
    gi_mean[b * Mm + m] = sum * (1.f / (float)Tt);
}

// ---------------------------------------------------------------------------
// Fused attention per (b, h) — fp32
// ---------------------------------------------------------------------------
__global__ __launch_bounds__(256)
void attn_kernel(const float* __restrict__ q, const float* __restrict__ k,
                 const float* __restrict__ v, float* __restrict__ att)
{
    const int b = blockIdx.x / Hh;
    const int h = blockIdx.x % Hh;
    const int tid = threadIdx.x;

    __shared__ float qs[Ss][KDd];
    __shared__ float sc[Ss][Tt];

    {
        int s  = tid / 32;
        int d4 = (tid % 32) * 4;
        float4 qv = *(const float4*)&q[((size_t)(b * Ss + s)) * Mm + h * KDd + d4];
        qs[s][d4 + 0] = qv.x; qs[s][d4 + 1] = qv.y;
        qs[s][d4 + 2] = qv.z; qs[s][d4 + 3] = qv.w;
    }
    __syncthreads();

#pragma unroll
    for (int half = 0; half < 2; ++half) {
        const int t = tid + half * 256;
        const float* kr = &k[((size_t)(b * Tt + t)) * Mm + h * KDd];
        float acc[Ss];
#pragma unroll
        for (int s = 0; s < Ss; ++s) acc[s] = 0.f;
        for (int d = 0; d < KDd; d += 4) {
            float4 kv = *(const float4*)(kr + d);
#pragma unroll
            for (int s = 0; s < Ss; ++s)
                acc[s] += qs[s][d + 0] * kv.x + qs[s][d + 1] * kv.y
                        + qs[s][d + 2] * kv.z + qs[s][d + 3] * kv.w;
        }
#pragma unroll
        for (int s = 0; s < Ss; ++s) sc[s][t] = acc[s];
    }
    __syncthreads();

    const int s    = tid >> 5;
    const int lane = tid & 31;
    float mx = -1e30f;
    for (int t = lane; t < Tt; t += 32) mx = fmaxf(mx, sc[s][t]);
#pragma unroll
    for (int m = 16; m >= 1; m >>= 1) mx = fmaxf(mx, __shfl_xor(mx, m));
    float sum = 0.f;
    for (int t = lane; t < Tt; t += 32) {
        float e = __expf(sc[s][t] - mx);
        sc[s][t] = e;
        sum += e;
    }
#pragma unroll
    for (int m = 16; m >= 1; m >>= 1) sum += __shfl_xor(sum, m);
    const float inv = 1.f / sum;
    __syncthreads();

    const int d0 = (tid & 31) * 4;
    const float* vb = &v[((size_t)(b * Tt)) * Mm + h * KDd + d0];
    float4 acc = make_float4(0.f, 0.f, 0.f, 0.f);
    for (int t = 0; t < Tt; ++t) {
        const float p = sc[s][t];
        float4 vv = *(const float4*)(vb + (size_t)t * Mm);
        acc.x = fmaf(p, vv.x, acc.x);
        acc.y = fmaf(p, vv.y, acc.y);
        acc.z = fmaf(p, vv.z, acc.z);
        acc.w = fmaf(p, vv.w, acc.w);
    }
    float4 o = make_float4(acc.x * inv, acc.y * inv, acc.z * inv, acc.w * inv);
    *(float4*)&att[((size_t)(b * Ss + s)) * Mm + h * KDd + d0] = o;
}

// ---------------------------------------------------------------------------
__global__ __launch_bounds__(256)
void ln_add(const float* __restrict__ a, const float* __restrict__ b,
            const float* __restrict__ g, const float* __restrict__ be,
            float* __restrict__ out)
{
    const int row = blockIdx.x;
    const int tid = threadIdx.x;
    const float* ap = a + (size_t)row * Mm;
    const float* bp = b + (size_t)row * Mm;

    float4 av = *(const float4*)&ap[tid * 4];
    float4 bv = *(const float4*)&bp[tid * 4];
    float x0 = av.x + bv.x, x1 = av.y + bv.y, x2 = av.z + bv.z, x3 = av.w + bv.w;
    float s  = x0 + x1 + x2 + x3;
    float ss = x0 * x0 + x1 * x1 + x2 * x2 + x3 * x3;
#pragma unroll
    for (int m = 32; m >= 1; m >>= 1) {
        s  += __shfl_xor(s, m);
        ss += __shfl_xor(ss, m);
    }
    __shared__ float red[2][4];
    const int wid = tid >> 6;
    if ((tid & 63) == 0) { red[0][wid] = s; red[1][wid] = ss; }
    __syncthreads();
    s  = red[0][0] + red[0][1] + red[0][2] + red[0][3];
    ss = red[1][0] + red[1][1] + red[1][2] + red[1][3];
    const float mu  = s * (1.f / (float)Mm);
    const float var = ss * (1.f / (float)Mm) - mu * mu;
    const float inv = rsqrtf(var + 1e-5f);

    float4 gv = *(const float4*)&g[tid * 4];
    float4 bev = *(const float4*)&be[tid * 4];
    float4 o;
    o.x = (x0 - mu) * inv * gv.x + bev.x;
    o.y = (x1 - mu) * inv * gv.y + bev.y;
    o.z = (x2 - mu) * inv * gv.z + bev.z;
    o.w = (x3 - mu) * inv * gv.w + bev.w;
    *(float4*)&out[(size_t)row * Mm + tid * 4] = o;
}

__global__ __launch_bounds__(256)
void tanh_kernel(const float* __restrict__ in, float* __restrict__ out)
{
    const int idx = blockIdx.x * 256 + threadIdx.x;
    out[idx] = tanhf(in[idx]);
}

__global__ __launch_bounds__(256)
void combine_kernel(const float* __restrict__ gm, const float* __restrict__ gi,
                    const float* __restrict__ nextm, const float* __restrict__ memory,
                    const float* __restrict__ ibp, const float* __restrict__ fbp,
                    float* __restrict__ out)
{
    const int idx = blockIdx.x * 256 + threadIdx.x;
    const int m  = idx & (Mm - 1);
    const int bs = idx >> 10;
    const int b  = bs >> 3;
    const float ib = ibp[0], fb = fbp[0];
    const float gmi = gm[(size_t)bs * NGg + m];
    const float gmf = gm[(size_t)bs * NGg + Mm + m];
    const float gii = gi[(size_t)b * NGg + m];
    const float gif = gi[(size_t)b * NGg + Mm + m];
    const float ig = 1.f / (1.f + __expf(-(gmi + gii + ib)));
    const float fg = 1.f / (1.f + __expf(-(gmf + gif + fb)));
    out[idx] = ig * tanhf(nextm[idx]) + fg * memory[idx];
}

// ---------------------------------------------------------------------------
extern "C" void kernel_launch(void* const* d_in, const int* in_sizes, int n_in,
                              void* d_out, int out_size, void* d_ws, size_t ws_size,
                              hipStream_t stream)
{
    const float* inputs = (const float*)d_in[0];
    const float* memory = (const float*)d_in[1];
    const float* Wp  = (const float*)d_in[2];
    const float* bp  = (const float*)d_in[3];
    const float* Wq  = (const float*)d_in[4];
    const float* bq  = (const float*)d_in[5];
    const float* Wk  = (const float*)d_in[6];
    const float* bk  = (const float*)d_in[7];
    const float* Wv  = (const float*)d_in[8];
    const float* bv  = (const float*)d_in[9];
    const float* Wm  = (const float*)d_in[10];
    const float* bm  = (const float*)d_in[11];
    const float* g1  = (const float*)d_in[12];
    const float* be1 = (const float*)d_in[13];
    const float* g2  = (const float*)d_in[14];
    const float* be2 = (const float*)d_in[15];
    const float* rl_w = (const float*)d_in[16];
    const float* rl_W = (const float*)d_in[17];
    const float* rl_b = (const float*)d_in[18];
    const float* gl_W = (const float*)d_in[19];
    const float* gl_b = (const float*)d_in[20];
    const float* ibp  = (const float*)d_in[21];
    const float* fbp  = (const float*)d_in[22];
    float* out = (float*)d_out;

    // ---- workspace layout (float units) ----
    const size_t N_SM = (size_t)Bq * Ss * Mm;     // 524,288
    float* ws = (float*)d_ws;
    float* qbuf   = ws;
    float* attb   = qbuf   + N_SM;
    float* mem1   = attb   + N_SM;
    float* mlp1   = mem1   + N_SM;
    float* mlp2   = mlp1   + N_SM;
    float* nextm  = mlp2   + N_SM;
    float* tm     = nextm  + N_SM;
    float* gimean = tm     + N_SM;
    float* gibuf  = gimean + (size_t)Bq * Mm;
    float* gmbuf  = gibuf  + (size_t)Bq * NGg;
    float* skp    = gmbuf  + (size_t)Bq * Ss * NGg;       // split-K partials
    const size_t SKP_FLOATS = (size_t)8 * 512 * 1024;     // 4.19M floats (max use)
    float* pconst = skp + SKP_FLOATS;
    // bf16 constants
    ushort* ib16 = (ushort*)pconst;                       // [B*T][DIN]
    ushort* WpT  = ib16 + (size_t)Bq * Tt * DIN;          // [M][DIN]
    ushort* WkT  = WpT  + (size_t)Mm * DIN;               // [M][M]
    ushort* WvT  = WkT  + (size_t)Mm * Mm;                // [M][M]
    ushort* cend = WvT  + (size_t)Mm * Mm;
    // chunk region start (float*, 16B aligned)
    size_t const_u16 = (size_t)(cend - (ushort*)pconst);
    size_t const_floats = (size_t)(pconst - ws) + (const_u16 + 1) / 2;
    const_floats = (const_floats + 3) & ~(size_t)3;       // 16B align
    float* cstart = ws + const_floats;

    // per-chunk: kbuf fp32 (Bc*T*M) + vbuf fp32 (Bc*T*M) + xb16 (Bc*T*M u16)
    int Bc = Bq;
    while (Bc > 1 &&
           (const_floats + (size_t)Bc * Tt * Mm * 5 / 2) * sizeof(float) > ws_size)
        Bc >>= 1;
    const size_t N_XC = (size_t)Bc * Tt * Mm;
    float*  kbuf = cstart;
    float*  vbuf = kbuf + N_XC;
    ushort* xb16 = (ushort*)(vbuf + N_XC);

    const dim3 blk(256);

    // ---- precompute bf16 operands ----
    conv_bf16<<<dim3((Bq * Tt * DIN) / 1024), blk, 0, stream>>>(inputs, ib16);
    transpose_to_bf16<<<dim3(Mm / 32, DIN / 32), blk, 0, stream>>>(Wp, WpT, DIN, Mm);
    transpose_to_bf16<<<dim3(Mm / 32, Mm / 32), blk, 0, stream>>>(Wk, WkT, Mm, Mm);
    transpose_to_bf16<<<dim3(Mm / 32, Mm / 32), blk, 0, stream>>>(Wv, WvT, Mm, Mm);

    // q = memory @ Wq + bq   (split-K=8)
    gemm_f32_sk<64,64,16,4,4,8><<<dim3(Mm/64, (Bq*Ss)/64, 8), blk, 0, stream>>>(
        memory, Mm, 0, Wq, Mm, 0, skp, Bq*Ss, Mm, Mm);
    sk_reduce<8,false><<<dim3((Bq*Ss*Mm)/1024), blk, 0, stream>>>(
        skp, bq, 0, qbuf, Mm, 0, (Bq*Ss*Mm)/4, Mm);

    // ---- chunked: x(bf16), k, v, gi_reduce, attention ----
    for (int c0 = 0; c0 < Bq; c0 += Bc) {
        const int rows = Bc * Tt;

        // x_bf16 = bf16(inputs_c @ Wp + bp)
        gemm_mfma<1><<<dim3(Mm/128, rows/128), blk, 0, stream>>>(
            ib16 + (size_t)c0 * Tt * DIN, WpT, bp, xb16, Mm, DIN);

        // k = x @ Wk + bk  (fp32 out)
        gemm_mfma<0><<<dim3(Mm/128, rows/128), blk, 0, stream>>>(
            xb16, WkT, bk, kbuf, Mm, Mm);

        // v = x @ Wv + bv
        gemm_mfma<0><<<dim3(Mm/128, rows/128), blk, 0, stream>>>(
            xb16, WvT, bv, vbuf, Mm, Mm);

        // gi_mean_c = mean_t relu(rl_w * x)
        gi_reduce<<<dim3(Bc * (Mm/256)), blk, 0, stream>>>(
            xb16, rl_w, gimean + (size_t)c0 * Mm);

        // attention for this chunk
        attn_kernel<<<dim3(Bc * Hh), blk, 0, stream>>>(
            qbuf + (size_t)c0 * Ss * Mm, kbuf, vbuf,
            attb + (size_t)c0 * Ss * Mm);
    }

    // mem1 = LN(memory + att)
    ln_add<<<dim3(Bq * Ss), blk, 0, stream>>>(memory, attb, g1, be1, mem1);

    // mlp1 = relu(mem1 @ Wm + bm)   (split-K=8)
    gemm_f32_sk<64,64,16,4,4,8><<<dim3(Mm/64, (Bq*Ss)/64, 8), blk, 0, stream>>>(
        mem1, Mm, 0, Wm, Mm, 0, skp, Bq*Ss, Mm, Mm);
    sk_reduce<8,true><<<dim3((Bq*Ss*Mm)/1024), blk, 0, stream>>>(
        skp, bm, 0, mlp1, Mm, 0, (Bq*Ss*Mm)/4, Mm);

    // mlp2 = relu(mlp1 @ Wm + bm)
    gemm_f32_sk<64,64,16,4,4,8><<<dim3(Mm/64, (Bq*Ss)/64, 8), blk, 0, stream>>>(
        mlp1, Mm, 0, Wm, Mm, 0, skp, Bq*Ss, Mm, Mm);
    sk_reduce<8,true><<<dim3((Bq*Ss*Mm)/1024), blk, 0, stream>>>(
        skp, bm, 0, mlp2, Mm, 0, (Bq*Ss*Mm)/4, Mm);

    // next = LN(mem1 + mlp2)
    ln_add<<<dim3(Bq * Ss), blk, 0, stream>>>(mem1, mlp2, g2, be2, nextm);

    // tm = tanh(memory)
    tanh_kernel<<<dim3((Bq*Ss*Mm)/256), blk, 0, stream>>>(memory, tm);

    // gm[:, s, :] = tm[:, s, :] @ gl_W[s] + gl_b[s]   (batch z=8, split-K=4)
    gemm_f32_sk<64,64,16,4,4,4><<<dim3(NGg/64, Bq/64, Ss*4), blk, 0, stream>>>(
        tm, Ss*Mm, (long long)Mm,
        gl_W, NGg, (long long)Mm * NGg,
        skp, Bq, NGg, Mm);
    sk_reduce<4,false><<<dim3((Ss*Bq*NGg)/1024), blk, 0, stream>>>(
        skp, gl_b, NGg, gmbuf, Ss*NGg, NGg, (Bq*NGg)/4, NGg);

    // gi = gi_mean @ rl_W + rl_b   (split-K=8)
    gemm_f32_sk<64,64,16,4,4,8><<<dim3(NGg/64, Bq/64, 8), blk, 0, stream>>>(
        gimean, Mm, 0, rl_W, NGg, 0, skp, Bq, NGg, Mm);
    sk_reduce<8,false><<<dim3((Bq*NGg)/1024), blk, 0, stream>>>(
        skp, rl_b, 0, gibuf, NGg, 0, (Bq*NGg)/4, NGg);

    // final gates + output
    combine_kernel<<<dim3((Bq*Ss*Mm)/256), blk, 0, stream>>>(
        gmbuf, gibuf, nextm, memory, ibp, fbp, out);
}

// Round 6
// 558.122 us; speedup vs baseline: 4.2547x; 1.1239x over previous
//
#include <hip/hip_runtime.h>
#include <hip/hip_bf16.h>

// Problem constants
#define Bq   64
#define Tt   512
#define DIN  512
#define Ss   8
#define HSs  128
#define Hh   8
#define Mm   1024
#define KDd  128
#define NGg  2048

typedef __attribute__((ext_vector_type(8))) short bf16x8;
typedef __attribute__((ext_vector_type(4))) float f32x4;

__device__ __forceinline__ ushort f2b(float f) {
    union { float f; unsigned u; } v; v.f = f;
    unsigned r = v.u + 0x7fffu + ((v.u >> 16) & 1u);   // RNE
    return (ushort)(r >> 16);
}
__device__ __forceinline__ float b2f(ushort b) {
    union { unsigned u; float f; } v; v.u = ((unsigned)b) << 16;
    return v.f;
}
// unpack a uint holding two bf16 (little-endian: low half = element 2i)
__device__ __forceinline__ float blo(unsigned u) {
    union { unsigned u; float f; } v; v.u = u << 16; return v.f;
}
__device__ __forceinline__ float bhi(unsigned u) {
    union { unsigned u; float f; } v; v.u = u & 0xffff0000u; return v.f;
}

#define GLOAD_LDS16(g, l) __builtin_amdgcn_global_load_lds( \
    (const __attribute__((address_space(1))) void*)(g),     \
    (__attribute__((address_space(3))) void*)(l), 16, 0, 0)

// ---------------------------------------------------------------------------
// bf16 MFMA GEMM (m97-style): 128x128 tile, BK=32, 4 waves, 64x64 per wave.
// A [rows][K] bf16 row-major; Bt [N][K] bf16 (B transposed, k contiguous);
// bias fp32 [N]. OUT_BF16: C written as bf16, else fp32.
// XCD-bijective blockIdx swizzle (m204): per-XCD contiguous row-panel chunks.
// ---------------------------------------------------------------------------
template<int OUT_BF16>
__global__ __launch_bounds__(256)
void gemm_mfma(const ushort* __restrict__ A, const ushort* __restrict__ Bt,
               const float* __restrict__ bias, void* __restrict__ Cout,
               int ldc, int Kdim)
{
    __shared__ __align__(16) ushort As[128 * 32];   // 8 KB
    __shared__ __align__(16) ushort Bs[128 * 32];   // 8 KB

    const int tid  = threadIdx.x;
    const int w    = tid >> 6;
    const int lane = tid & 63;

    // ---- bijective XCD swizzle (T1, m204) ----
    const int gx   = gridDim.x;
    const int nwg  = gx * gridDim.y;
    const int orig = blockIdx.y * gx + blockIdx.x;
    const int q8   = nwg >> 3, r8 = nwg & 7;
    const int xcd  = orig & 7, idx8 = orig >> 3;
    const int swz  = (xcd < r8 ? xcd * (q8 + 1)
                               : r8 * (q8 + 1) + (xcd - r8) * q8) + idx8;
    const int row0 = (swz / gx) * 128;
    const int col0 = (swz % gx) * 128;
    const int wr   = w >> 1, wc = w & 1;

    f32x4 acc[4][4];
#pragma unroll
    for (int i = 0; i < 4; ++i)
#pragma unroll
        for (int j = 0; j < 4; ++j) acc[i][j] = (f32x4){0.f, 0.f, 0.f, 0.f};

    // staging: chunk c = is*256 + tid; row = c/4, k-quarter = (c&3)*8
    const ushort* Ag = A  + (size_t)(row0 + (tid >> 2)) * Kdim + (tid & 3) * 8;
    const ushort* Bg = Bt + (size_t)(col0 + (tid >> 2)) * Kdim + (tid & 3) * 8;

    for (int k0 = 0; k0 < Kdim; k0 += 32) {
        __syncthreads();
#pragma unroll
        for (int is = 0; is < 2; ++is)
            GLOAD_LDS16(Ag + (size_t)is * 64 * Kdim + k0,
                        (char*)As + (is * 256 + w * 64) * 16);
#pragma unroll
        for (int is = 0; is < 2; ++is)
            GLOAD_LDS16(Bg + (size_t)is * 64 * Kdim + k0,
                        (char*)Bs + (is * 256 + w * 64) * 16);
        asm volatile("s_waitcnt vmcnt(0)" ::: "memory");
        __syncthreads();

        bf16x8 a[4], b[4];
#pragma unroll
        for (int i = 0; i < 4; ++i) {
            a[i] = *(const bf16x8*)&As[(wr * 64 + i * 16 + (lane & 15)) * 32 + (lane >> 4) * 8];
            b[i] = *(const bf16x8*)&Bs[(wc * 64 + i * 16 + (lane & 15)) * 32 + (lane >> 4) * 8];
        }
#pragma unroll
        for (int i = 0; i < 4; ++i)
#pragma unroll
            for (int j = 0; j < 4; ++j)
                acc[i][j] = __builtin_amdgcn_mfma_f32_16x16x32_bf16(a[i], b[j], acc[i][j], 0, 0, 0);
    }

    // epilogue: D row = wr*64+i*16+(lane>>4)*4+r ; col = wc*64+j*16+(lane&15)
    float bsv[4];
#pragma unroll
    for (int j = 0; j < 4; ++j) bsv[j] = bias[col0 + wc * 64 + j * 16 + (lane & 15)];
#pragma unroll
    for (int i = 0; i < 4; ++i) {
        const int row = row0 + wr * 64 + i * 16 + (lane >> 4) * 4;
        const int col = col0 + wc * 64 + (lane & 15);
#pragma unroll
        for (int r = 0; r < 4; ++r) {
            const size_t off = (size_t)(row + r) * ldc + col;
#pragma unroll
            for (int j = 0; j < 4; ++j) {
                float vv = acc[i][j][r] + bsv[j];
                if (OUT_BF16) ((ushort*)Cout)[off + j * 16] = f2b(vv);
                else          ((float*)Cout)[off + j * 16]  = vv;
            }
        }
    }
}

// ---------------------------------------------------------------------------
// transpose + convert: out[C][R] bf16 = in[R][C] fp32   (R,C multiples of 32)
// ---------------------------------------------------------------------------
__global__ __launch_bounds__(256)
void transpose_to_bf16(const float* __restrict__ in, ushort* __restrict__ out,
                       int R, int C)
{
    __shared__ float t[32][33];
    const int c0 = blockIdx.x * 32, r0 = blockIdx.y * 32;
    const int tx = threadIdx.x & 31, ty = threadIdx.x >> 5;   // 32 x 8
#pragma unroll
    for (int i = 0; i < 32; i += 8)
        t[ty + i][tx] = in[(size_t)(r0 + ty + i) * C + c0 + tx];
    __syncthreads();
#pragma unroll
    for (int i = 0; i < 32; i += 8)
        out[(size_t)(c0 + ty + i) * R + r0 + tx] = f2b(t[tx][ty + i]);
}

// elementwise fp32 -> bf16 (n divisible by 1024)
__global__ __launch_bounds__(256)
void conv_bf16(const float* __restrict__ in, ushort* __restrict__ out)
{
    const int i = blockIdx.x * 256 + threadIdx.x;
    float4 v = ((const float4*)in)[i];
    ushort4 o;
    o.x = f2b(v.x); o.y = f2b(v.y); o.z = f2b(v.z); o.w = f2b(v.w);
    ((ushort4*)out)[i] = o;
}

// concat two [Mm] bias vectors into one [2*Mm]
__global__ __launch_bounds__(256)
void concat2(const float* __restrict__ a, const float* __restrict__ b,
             float* __restrict__ o)
{
    const int i = blockIdx.x * 256 + threadIdx.x;
    o[i] = (i < Mm) ? a[i] : b[i - Mm];
}

// ---------------------------------------------------------------------------
// Split-K fp32 GEMM: partials P[zz][Mrows][Ncols], zz = batch*SPLITK + ks.
// ---------------------------------------------------------------------------
template<int BM, int BN, int BK, int TM, int TN, int SPLITK>
__global__ __launch_bounds__(256)
void gemm_f32_sk(const float* __restrict__ A, int lda, long long sA,
                 const float* __restrict__ B, int ldb, long long sB,
                 float* __restrict__ P, int Mrows, int Ncols, int Kdim)
{
    constexpr int TX = BN / TN;
    constexpr int TY = BM / TM;
    static_assert(TX * TY == 256, "256 threads");
    constexpr int KC4   = BK / 4;
    constexpr int A_PER = (BM * BK / 4) / 256;
    constexpr int B_PER = (BK * BN / 4) / 256;

    __shared__ float As[BK][BM + 4];
    __shared__ float Bs[BK][BN];

    const int tid = threadIdx.x;
    const int tx  = tid % TX;
    const int ty  = tid / TX;
    const int zz  = blockIdx.z;
    const int zb  = zz / SPLITK;
    const int ks  = zz % SPLITK;
    A += (long long)zb * sA;
    B += (long long)zb * sB;
    const int Kslice = Kdim / SPLITK;
    const int kbeg = ks * Kslice, kend = kbeg + Kslice;
    const int row0 = blockIdx.y * BM;
    const int col0 = blockIdx.x * BN;

    float acc[TM][TN];
#pragma unroll
    for (int i = 0; i < TM; ++i)
#pragma unroll
        for (int j = 0; j < TN; ++j) acc[i][j] = 0.f;

    for (int k0 = kbeg; k0 < kend; k0 += BK) {
        __syncthreads();
#pragma unroll
        for (int l = 0; l < A_PER; ++l) {
            int idx = tid + l * 256;
            int ar  = idx / KC4;
            int ac  = (idx % KC4) * 4;
            float4 va = *(const float4*)&A[(long long)(row0 + ar) * lda + k0 + ac];
            As[ac + 0][ar] = va.x;
            As[ac + 1][ar] = va.y;
            As[ac + 2][ar] = va.z;
            As[ac + 3][ar] = va.w;
        }
#pragma unroll
        for (int l = 0; l < B_PER; ++l) {
            int idx = tid + l * 256;
            int br  = idx / (BN / 4);
            int bc  = (idx % (BN / 4)) * 4;
            *(float4*)&Bs[br][bc] = *(const float4*)&B[(long long)(k0 + br) * ldb + col0 + bc];
        }
        __syncthreads();
#pragma unroll
        for (int k = 0; k < BK; ++k) {
            float a[TM], b[TN];
#pragma unroll
            for (int i = 0; i < TM; i += 4)
                *(float4*)&a[i] = *(const float4*)&As[k][ty * TM + i];
#pragma unroll
            for (int j = 0; j < TN; j += 4)
                *(float4*)&b[j] = *(const float4*)&Bs[k][tx * TN + j];
#pragma unroll
            for (int i = 0; i < TM; ++i)
#pragma unroll
                for (int j = 0; j < TN; ++j)
                    acc[i][j] = fmaf(a[i], b[j], acc[i][j]);
        }
    }

    float* Pz = P + (size_t)zz * Mrows * Ncols;
#pragma unroll
    for (int i = 0; i < TM; ++i) {
        const size_t prow = (size_t)(row0 + ty * TM + i) * Ncols;
#pragma unroll
        for (int j = 0; j < TN; j += 4)
            *(float4*)&Pz[prow + col0 + tx * TN + j] = *(const float4*)&acc[i][j];
    }
}

// ---------------------------------------------------------------------------
// sk_reduce: C[batch][row][col] = (relu?)( sum_ks P + bias[batch][col] )
// ---------------------------------------------------------------------------
template<int SPLITK, bool RELU>
__global__ __launch_bounds__(256)
void sk_reduce(const float* __restrict__ P, const float* __restrict__ bias,
               long long sBias, float* __restrict__ C, int ldc, long long sC,
               int pb4, int Ncols)
{
    const int gid = blockIdx.x * 256 + threadIdx.x;
    const int batch = gid / pb4;
    const int r4    = gid % pb4;
    const float4* Pb = (const float4*)P + (size_t)batch * SPLITK * pb4 + r4;
    float4 s = Pb[0];
#pragma unroll
    for (int ks = 1; ks < SPLITK; ++ks) {
        float4 p = Pb[(size_t)ks * pb4];
        s.x += p.x; s.y += p.y; s.z += p.z; s.w += p.w;
    }
    const int col = (r4 * 4) % Ncols;
    const int row = (r4 * 4) / Ncols;
    float4 bv = *(const float4*)&bias[batch * sBias + col];
    s.x += bv.x; s.y += bv.y; s.z += bv.z; s.w += bv.w;
    if (RELU) {
        s.x = fmaxf(s.x, 0.f); s.y = fmaxf(s.y, 0.f);
        s.z = fmaxf(s.z, 0.f); s.w = fmaxf(s.w, 0.f);
    }
    *(float4*)&C[(size_t)batch * sC + (size_t)row * ldc + col] = s;
}

// ---------------------------------------------------------------------------
// gi_mean[b, m] = (1/T) * sum_t relu(rl_w[m] * x_bf16[b, t, m])
// ---------------------------------------------------------------------------
__global__ __launch_bounds__(256)
void gi_reduce(const ushort* __restrict__ x, const float* __restrict__ rl_w,
               float* __restrict__ gi_mean)
{
    const int b    = blockIdx.x / (Mm / 256);
    const int mblk = blockIdx.x % (Mm / 256);
    const int m    = mblk * 256 + threadIdx.x;
    const float w  = rl_w[m];
    const ushort* xp = x + (size_t)b * Tt * Mm + m;
    float sum = 0.f;
    for (int t = 0; t < Tt; ++t)
        sum += fmaxf(w * b2f(xp[(size_t)t * Mm]), 0.f);
    gi_mean[b * Mm + m] = sum * (1.f / (float)Tt);
}

// ---------------------------------------------------------------------------
// Fused attention per (b, h): q fp32 [.,S,M]; kv bf16 [.,T,2M] (k cols 0..M-1,
// v cols M..2M-1). b is chunk-local; q/att pre-offset. No 1/sqrt(d) scale.
// ---------------------------------------------------------------------------
__global__ __launch_bounds__(256)
void attn_kernel(const float* __restrict__ q, const ushort* __restrict__ kv,
                 float* __restrict__ att)
{
    const int b = blockIdx.x / Hh;
    const int h = blockIdx.x % Hh;
    const int tid = threadIdx.x;

    __shared__ float qs[Ss][KDd];     // 4 KB
    __shared__ float sc[Ss][Tt];      // 16 KB

    {
        int s  = tid / 32;
        int d4 = (tid % 32) * 4;
        float4 qv = *(const float4*)&q[((size_t)(b * Ss + s)) * Mm + h * KDd + d4];
        qs[s][d4 + 0] = qv.x; qs[s][d4 + 1] = qv.y;
        qs[s][d4 + 2] = qv.z; qs[s][d4 + 3] = qv.w;
    }
    __syncthreads();

    // scores: each thread computes column t for all 8 rows; two halves
#pragma unroll
    for (int half = 0; half < 2; ++half) {
        const int t = tid + half * 256;
        const ushort* kr = kv + ((size_t)(b * Tt + t)) * (2 * Mm) + h * KDd;
        float acc[Ss];
#pragma unroll
        for (int s = 0; s < Ss; ++s) acc[s] = 0.f;
        for (int d = 0; d < KDd; d += 8) {
            uint4 u = *(const uint4*)(kr + d);
            float k0 = blo(u.x), k1 = bhi(u.x), k2 = blo(u.y), k3 = bhi(u.y);
            float k4 = blo(u.z), k5 = bhi(u.z), k6 = blo(u.w), k7 = bhi(u.w);
#pragma unroll
            for (int s = 0; s < Ss; ++s)
                acc[s] += qs[s][d + 0] * k0 + qs[s][d + 1] * k1
                        + qs[s][d + 2] * k2 + qs[s][d + 3] * k3
                        + qs[s][d + 4] * k4 + qs[s][d + 5] * k5
                        + qs[s][d + 6] * k6 + qs[s][d + 7] * k7;
        }
#pragma unroll
        for (int s = 0; s < Ss; ++s) sc[s][t] = acc[s];
    }
    __syncthreads();

    // softmax: 8 groups of 32 lanes
    const int s    = tid >> 5;
    const int lane = tid & 31;
    float mx = -1e30f;
    for (int t = lane; t < Tt; t += 32) mx = fmaxf(mx, sc[s][t]);
#pragma unroll
    for (int m = 16; m >= 1; m >>= 1) mx = fmaxf(mx, __shfl_xor(mx, m));
    float sum = 0.f;
    for (int t = lane; t < Tt; t += 32) {
        float e = __expf(sc[s][t] - mx);
        sc[s][t] = e;
        sum += e;
    }
#pragma unroll
    for (int m = 16; m >= 1; m >>= 1) sum += __shfl_xor(sum, m);
    const float inv = 1.f / sum;
    __syncthreads();

    // PV: thread computes att[s, d0..d0+3]
    const int d0 = (tid & 31) * 4;
    const ushort* vb = kv + ((size_t)(b * Tt)) * (2 * Mm) + Mm + h * KDd + d0;
    float4 acc = make_float4(0.f, 0.f, 0.f, 0.f);
    for (int t = 0; t < Tt; ++t) {
        const float p = sc[s][t];
        uint2 u = *(const uint2*)(vb + (size_t)t * (2 * Mm));
        acc.x = fmaf(p, blo(u.x), acc.x);
        acc.y = fmaf(p, bhi(u.x), acc.y);
        acc.z = fmaf(p, blo(u.y), acc.z);
        acc.w = fmaf(p, bhi(u.y), acc.w);
    }
    float4 o = make_float4(acc.x * inv, acc.y * inv, acc.z * inv, acc.w * inv);
    *(float4*)&att[((size_t)(b * Ss + s)) * Mm + h * KDd + d0] = o;
}

// ---------------------------------------------------------------------------
__global__ __launch_bounds__(256)
void ln_add(const float* __restrict__ a, const float* __restrict__ b,
            const float* __restrict__ g, const float* __restrict__ be,
            float* __restrict__ out)
{
    const int row = blockIdx.x;
    const int tid = threadIdx.x;
    const float* ap = a + (size_t)row * Mm;
    const float* bp = b + (size_t)row * Mm;

    float4 av = *(const float4*)&ap[tid * 4];
    float4 bv = *(const float4*)&bp[tid * 4];
    float x0 = av.x + bv.x, x1 = av.y + bv.y, x2 = av.z + bv.z, x3 = av.w + bv.w;
    float s  = x0 + x1 + x2 + x3;
    float ss = x0 * x0 + x1 * x1 + x2 * x2 + x3 * x3;
#pragma unroll
    for (int m = 32; m >= 1; m >>= 1) {
        s  += __shfl_xor(s, m);
        ss += __shfl_xor(ss, m);
    }
    __shared__ float red[2][4];
    const int wid = tid >> 6;
    if ((tid & 63) == 0) { red[0][wid] = s; red[1][wid] = ss; }
    __syncthreads();
    s  = red[0][0] + red[0][1] + red[0][2] + red[0][3];
    ss = red[1][0] + red[1][1] + red[1][2] + red[1][3];
    const float mu  = s * (1.f / (float)Mm);
    const float var = ss * (1.f / (float)Mm) - mu * mu;
    const float inv = rsqrtf(var + 1e-5f);

    float4 gv = *(const float4*)&g[tid * 4];
    float4 bev = *(const float4*)&be[tid * 4];
    float4 o;
    o.x = (x0 - mu) * inv * gv.x + bev.x;
    o.y = (x1 - mu) * inv * gv.y + bev.y;
    o.z = (x2 - mu) * inv * gv.z + bev.z;
    o.w = (x3 - mu) * inv * gv.w + bev.w;
    *(float4*)&out[(size_t)row * Mm + tid * 4] = o;
}

__global__ __launch_bounds__(256)
void tanh_kernel(const float* __restrict__ in, float* __restrict__ out)
{
    const int idx = blockIdx.x * 256 + threadIdx.x;
    out[idx] = tanhf(in[idx]);
}

__global__ __launch_bounds__(256)
void combine_kernel(const float* __restrict__ gm, const float* __restrict__ gi,
                    const float* __restrict__ nextm, const float* __restrict__ memory,
                    const float* __restrict__ ibp, const float* __restrict__ fbp,
                    float* __restrict__ out)
{
    const int idx = blockIdx.x * 256 + threadIdx.x;
    const int m  = idx & (Mm - 1);
    const int bs = idx >> 10;
    const int b  = bs >> 3;
    const float ib = ibp[0], fb = fbp[0];
    const float gmi = gm[(size_t)bs * NGg + m];
    const float gmf = gm[(size_t)bs * NGg + Mm + m];
    const float gii = gi[(size_t)b * NGg + m];
    const float gif = gi[(size_t)b * NGg + Mm + m];
    const float ig = 1.f / (1.f + __expf(-(gmi + gii + ib)));
    const float fg = 1.f / (1.f + __expf(-(gmf + gif + fb)));
    out[idx] = ig * tanhf(nextm[idx]) + fg * memory[idx];
}

// ---------------------------------------------------------------------------
extern "C" void kernel_launch(void* const* d_in, const int* in_sizes, int n_in,
                              void* d_out, int out_size, void* d_ws, size_t ws_size,
                              hipStream_t stream)
{
    const float* inputs = (const float*)d_in[0];
    const float* memory = (const float*)d_in[1];
    const float* Wp  = (const float*)d_in[2];
    const float* bp  = (const float*)d_in[3];
    const float* Wq  = (const float*)d_in[4];
    const float* bq  = (const float*)d_in[5];
    const float* Wk  = (const float*)d_in[6];
    const float* bk  = (const float*)d_in[7];
    const float* Wv  = (const float*)d_in[8];
    const float* bv  = (const float*)d_in[9];
    const float* Wm  = (const float*)d_in[10];
    const float* bm  = (const float*)d_in[11];
    const float* g1  = (const float*)d_in[12];
    const float* be1 = (const float*)d_in[13];
    const float* g2  = (const float*)d_in[14];
    const float* be2 = (const float*)d_in[15];
    const float* rl_w = (const float*)d_in[16];
    const float* rl_W = (const float*)d_in[17];
    const float* rl_b = (const float*)d_in[18];
    const float* gl_W = (const float*)d_in[19];
    const float* gl_b = (const float*)d_in[20];
    const float* ibp  = (const float*)d_in[21];
    const float* fbp  = (const float*)d_in[22];
    float* out = (float*)d_out;

    // ---- workspace layout (float units) ----
    const size_t N_SM = (size_t)Bq * Ss * Mm;     // 524,288
    float* ws = (float*)d_ws;
    float* qbuf   = ws;
    float* attb   = qbuf   + N_SM;
    float* mem1   = attb   + N_SM;
    float* mlp1   = mem1   + N_SM;
    float* mlp2   = mlp1   + N_SM;
    float* nextm  = mlp2   + N_SM;
    float* tm     = nextm  + N_SM;
    float* gimean = tm     + N_SM;
    float* gibuf  = gimean + (size_t)Bq * Mm;
    float* gmbuf  = gibuf  + (size_t)Bq * NGg;
    float* skp    = gmbuf  + (size_t)Bq * Ss * NGg;       // split-K partials
    const size_t SKP_FLOATS = (size_t)8 * 512 * 1024;     // 4.19M floats (max use)
    float* bkv    = skp + SKP_FLOATS;                     // [2048] concat bias
    float* pconst = bkv + NGg;
    // bf16 constants
    ushort* ib16 = (ushort*)pconst;                       // [B*T][DIN]
    ushort* WpT  = ib16 + (size_t)Bq * Tt * DIN;          // [M][DIN]
    ushort* WkvT = WpT  + (size_t)Mm * DIN;               // [2M][M]: WkT then WvT
    ushort* cend = WkvT + (size_t)2 * Mm * Mm;
    // chunk region start (float*, 16B aligned)
    size_t const_u16 = (size_t)(cend - (ushort*)pconst);
    size_t const_floats = (size_t)(pconst - ws) + (const_u16 + 1) / 2;
    const_floats = (const_floats + 3) & ~(size_t)3;       // 16B align
    float* cstart = ws + const_floats;

    // per-chunk: kv bf16 (Bc*T*2M u16 = Bc*T*M floats) + xb16 (Bc*T*M u16)
    int Bc = Bq;
    while (Bc > 1 &&
           (const_floats + (size_t)Bc * Tt * Mm * 3 / 2) * sizeof(float) > ws_size)
        Bc >>= 1;
    const size_t N_XC = (size_t)Bc * Tt * Mm;
    ushort* kvb16 = (ushort*)cstart;                      // [Bc*T][2M]
    ushort* xb16  = kvb16 + 2 * N_XC;                     // [Bc*T][M]

    const dim3 blk(256);

    // ---- precompute bf16 operands + concat bias ----
    conv_bf16<<<dim3((Bq * Tt * DIN) / 1024), blk, 0, stream>>>(inputs, ib16);
    transpose_to_bf16<<<dim3(Mm / 32, DIN / 32), blk, 0, stream>>>(Wp, WpT, DIN, Mm);
    transpose_to_bf16<<<dim3(Mm / 32, Mm / 32), blk, 0, stream>>>(Wk, WkvT, Mm, Mm);
    transpose_to_bf16<<<dim3(Mm / 32, Mm / 32), blk, 0, stream>>>(Wv, WkvT + (size_t)Mm * Mm, Mm, Mm);
    concat2<<<dim3(NGg / 256), blk, 0, stream>>>(bk, bv, bkv);

    // q = memory @ Wq + bq   (split-K=8)
    gemm_f32_sk<64,64,16,4,4,8><<<dim3(Mm/64, (Bq*Ss)/64, 8), blk, 0, stream>>>(
        memory, Mm, 0, Wq, Mm, 0, skp, Bq*Ss, Mm, Mm);
    sk_reduce<8,false><<<dim3((Bq*Ss*Mm)/1024), blk, 0, stream>>>(
        skp, bq, 0, qbuf, Mm, 0, (Bq*Ss*Mm)/4, Mm);

    // ---- chunked: x(bf16), kv(bf16), gi_reduce, attention ----
    for (int c0 = 0; c0 < Bq; c0 += Bc) {
        const int rows = Bc * Tt;

        // x_bf16 = bf16(inputs_c @ Wp + bp)
        gemm_mfma<1><<<dim3(Mm/128, rows/128), blk, 0, stream>>>(
            ib16 + (size_t)c0 * Tt * DIN, WpT, bp, xb16, Mm, DIN);

        // kv = bf16(x @ [Wk|Wv] + [bk|bv])   (fused, N=2048)
        gemm_mfma<1><<<dim3((2*Mm)/128, rows/128), blk, 0, stream>>>(
            xb16, WkvT, bkv, kvb16, 2*Mm, Mm);

        // gi_mean_c = mean_t relu(rl_w * x)
        gi_reduce<<<dim3(Bc * (Mm/256)), blk, 0, stream>>>(
            xb16, rl_w, gimean + (size_t)c0 * Mm);

        // attention for this chunk
        attn_kernel<<<dim3(Bc * Hh), blk, 0, stream>>>(
            qbuf + (size_t)c0 * Ss * Mm, kvb16,
            attb + (size_t)c0 * Ss * Mm);
    }

    // mem1 = LN(memory + att)
    ln_add<<<dim3(Bq * Ss), blk, 0, stream>>>(memory, attb, g1, be1, mem1);

    // mlp1 = relu(mem1 @ Wm + bm)   (split-K=8)
    gemm_f32_sk<64,64,16,4,4,8><<<dim3(Mm/64, (Bq*Ss)/64, 8), blk, 0, stream>>>(
        mem1, Mm, 0, Wm, Mm, 0, skp, Bq*Ss, Mm, Mm);
    sk_reduce<8,true><<<dim3((Bq*Ss*Mm)/1024), blk, 0, stream>>>(
        skp, bm, 0, mlp1, Mm, 0, (Bq*Ss*Mm)/4, Mm);

    // mlp2 = relu(mlp1 @ Wm + bm)
    gemm_f32_sk<64,64,16,4,4,8><<<dim3(Mm/64, (Bq*Ss)/64, 8), blk, 0, stream>>>(
        mlp1, Mm, 0, Wm, Mm, 0, skp, Bq*Ss, Mm, Mm);
    sk_reduce<8,true><<<dim3((Bq*Ss*Mm)/1024), blk, 0, stream>>>(
        skp, bm, 0, mlp2, Mm, 0, (Bq*Ss*Mm)/4, Mm);

    // next = LN(mem1 + mlp2)
    ln_add<<<dim3(Bq * Ss), blk, 0, stream>>>(mem1, mlp2, g2, be2, nextm);

    // tm = tanh(memory)
    tanh_kernel<<<dim3((Bq*Ss*Mm)/256), blk, 0, stream>>>(memory, tm);

    // gm[:, s, :] = tm[:, s, :] @ gl_W[s] + gl_b[s]   (batch z=8, split-K=4)
    gemm_f32_sk<64,64,16,4,4,4><<<dim3(NGg/64, Bq/64, Ss*4), blk, 0, stream>>>(
        tm, Ss*Mm, (long long)Mm,
        gl_W, NGg, (long long)Mm * NGg,
        skp, Bq, NGg, Mm);
    sk_reduce<4,false><<<dim3((Ss*Bq*NGg)/1024), blk, 0, stream>>>(
        skp, gl_b, NGg, gmbuf, Ss*NGg, NGg, (Bq*NGg)/4, NGg);

    // gi = gi_mean @ rl_W + rl_b   (split-K=8)
    gemm_f32_sk<64,64,16,4,4,8><<<dim3(NGg/64, Bq/64, 8), blk, 0, stream>>>(
        gimean, Mm, 0, rl_W, NGg, 0, skp, Bq, NGg, Mm);
    sk_reduce<8,false><<<dim3((Bq*NGg)/1024), blk, 0, stream>>>(
        skp, rl_b, 0, gibuf, NGg, 0, (Bq*NGg)/4, NGg);

    // final gates + output
    combine_kernel<<<dim3((Bq*Ss*Mm)/256), blk, 0, stream>>>(
        gmbuf, gibuf, nextm, memory, ibp, fbp, out);
}

// Round 7
// 516.107 us; speedup vs baseline: 4.6010x; 1.0814x over previous
//
#include <hip/hip_runtime.h>
#include <hip/hip_bf16.h>

// Problem constants
#define Bq   64
#define Tt   512
#define DIN  512
#define Ss   8
#define HSs  128
#define Hh   8
#define Mm   1024
#define KDd  128
#define NGg  2048

typedef __attribute__((ext_vector_type(8))) short bf16x8;
typedef __attribute__((ext_vector_type(4))) float f32x4;

__device__ __forceinline__ ushort f2b(float f) {
    union { float f; unsigned u; } v; v.f = f;
    unsigned r = v.u + 0x7fffu + ((v.u >> 16) & 1u);   // RNE
    return (ushort)(r >> 16);
}
__device__ __forceinline__ float b2f(ushort b) {
    union { unsigned u; float f; } v; v.u = ((unsigned)b) << 16;
    return v.f;
}
__device__ __forceinline__ float blo(unsigned u) {
    union { unsigned u; float f; } v; v.u = u << 16; return v.f;
}
__device__ __forceinline__ float bhi(unsigned u) {
    union { unsigned u; float f; } v; v.u = u & 0xffff0000u; return v.f;
}

#define GLOAD_LDS16(g, l) __builtin_amdgcn_global_load_lds( \
    (const __attribute__((address_space(1))) void*)(g),     \
    (__attribute__((address_space(3))) void*)(l), 16, 0, 0)

// ---------------------------------------------------------------------------
// 8-phase 256x256 bf16 MFMA GEMM (T1+T2+T3+T4+T5), BK=64, 512 threads (8 waves
// as 2x4), per-wave output 128x64 split as 4 phase-pieces of 64x32.
// LDS 128 KiB: A/B regions, each 2 bufs x 2 half-tiles x (128 x 64bf16) =16KB.
// Phase p of K-tile U: (mu=p&1, nu=p>>1) uses A-half mu + B-half nu.
//   Stage schedule (1 half-tile per phase, counted vmcnt(4) once per K-tile):
//   p0: A-hi(U+1), p1: B-hi(U+1), p2: B-lo(U+2), p3: A-lo(U+2).
//   WAR-safe: each slot's stage phase is strictly after its last-read phase
//   (A-lo read p0,p2; A-hi p1,p3; B-lo p0,p1; B-hi p2,p3), barrier between.
//   vmcnt(4) at each tile end leaves exactly {B-lo,A-lo}(U+2) in flight.
// T2 swizzle: LDS slot (row r, 16B-slot q) holds global k-slot q^(r&7);
//   achieved by pre-swizzled per-lane global source (linear LDS dest) and the
//   same XOR on the read side (both-sides involution, rule #21).
// A [rows][K] bf16 row-major; Bt [N][K] bf16; bias fp32 [N]; C bf16 or fp32.
// Requires: rows%256==0, N%256==0, K%64==0, K/64 >= 3.
// ---------------------------------------------------------------------------
template<int OUT_BF16>
__global__ __launch_bounds__(512)
void gemm_8ph(const ushort* __restrict__ A, const ushort* __restrict__ Bt,
              const float* __restrict__ bias, void* __restrict__ Cout,
              int ldc, int Kdim)
{
    extern __shared__ __align__(16) char lds[];   // 131072 bytes

    const int tid  = threadIdx.x;
    const int wid  = tid >> 6;
    const int lane = tid & 63;
    const int wy   = wid >> 2;          // 0..1: row 64-block within 128-piece
    const int wx   = wid & 3;           // 0..3: col 32-block within 128-piece

    // ---- bijective XCD swizzle (T1, m204) ----
    const int gx   = gridDim.x;
    const int nwg  = gx * gridDim.y;
    const int orig = blockIdx.y * gx + blockIdx.x;
    const int q8   = nwg >> 3, r8 = nwg & 7;
    const int xcd  = orig & 7, idx8 = orig >> 3;
    const int swz  = (xcd < r8 ? xcd * (q8 + 1)
                               : r8 * (q8 + 1) + (xcd - r8) * q8) + idx8;
    const int row0 = (swz / gx) * 256;
    const int col0 = (swz % gx) * 256;

    const int NT = Kdim >> 6;

    // ---- staging source (pre-swizzled global address; LDS dest linear) ----
    // chunk c = l*512 + tid: r = c>>3 (l=1 adds 64), q = c&7; q' = q ^ (r&7)
    const int sr = tid >> 3;
    const int sq = (tid & 7) ^ (sr & 7);
    const ushort* Asrc = A  + (size_t)(row0 + sr) * Kdim + sq * 8;
    const ushort* Bsrc = Bt + (size_t)(col0 + sr) * Kdim + sq * 8;
    const int ldsw = wid * 1024;        // wave-uniform LDS offset (wid*64*16)

    auto stage = [&](int isB, int U, int h) {
        const ushort* s = (isB ? Bsrc : Asrc) + (size_t)h * 128 * Kdim
                        + (size_t)U * 64;
        char* d = lds + (isB ? 65536 : 0) + ((((U) & 1) * 2 + h) << 14) + ldsw;
        GLOAD_LDS16(s, d);
        GLOAD_LDS16(s + (size_t)64 * Kdim, d + 8192);
    };

    // ---- read-side swizzled lane offsets (precomputed, phase-invariant) ----
    const int l15   = lane & 15;
    const int s0_16 = (((lane >> 4)) ^ (lane & 7)) << 4;        // kk=0 slot*16
    const int s1_16 = ((4 + (lane >> 4)) ^ (lane & 7)) << 4;    // kk=1 slot*16
    const int aoff  = wy * 8192 + l15 * 128;    // wave row block + lane row
    const int boff  = wx * 4096 + l15 * 128;    // wave col block + lane col

    f32x4 acc[4][4][2];
#pragma unroll
    for (int p = 0; p < 4; ++p)
#pragma unroll
        for (int m = 0; m < 4; ++m)
#pragma unroll
            for (int n = 0; n < 2; ++n) acc[p][m][n] = (f32x4){0.f,0.f,0.f,0.f};

    // ---- prologue: T0 all 4 halves + T1 {B-lo, A-lo}; keep last 4 loads flying
    stage(0, 0, 0); stage(0, 0, 1); stage(1, 0, 0); stage(1, 0, 1);
    stage(1, 1, 0); stage(0, 1, 0);
    asm volatile("s_waitcnt vmcnt(4)" ::: "memory");
    __builtin_amdgcn_s_barrier();
    asm volatile("" ::: "memory");

    for (int U = 0; U < NT; ++U) {
        const char* Abase = lds + ((U & 1) << 15);
        const char* Bbase = lds + 65536 + ((U & 1) << 15);
#pragma unroll
        for (int p = 0; p < 4; ++p) {
            const char* pa0 = Abase + ((p & 1) << 14) + aoff + s0_16;
            const char* pa1 = Abase + ((p & 1) << 14) + aoff + s1_16;
            const char* pb0 = Bbase + ((p >> 1) << 14) + boff + s0_16;
            const char* pb1 = Bbase + ((p >> 1) << 14) + boff + s1_16;
            bf16x8 a[4][2], b[2][2];
#pragma unroll
            for (int m = 0; m < 4; ++m) {
                a[m][0] = *(const bf16x8*)(pa0 + m * 2048);
                a[m][1] = *(const bf16x8*)(pa1 + m * 2048);
            }
#pragma unroll
            for (int n = 0; n < 2; ++n) {
                b[n][0] = *(const bf16x8*)(pb0 + n * 2048);
                b[n][1] = *(const bf16x8*)(pb1 + n * 2048);
            }
            // one half-tile stage per phase (guarded near the tail)
            if      (p == 0) { if (U + 1 < NT) stage(0, U + 1, 1); }
            else if (p == 1) { if (U + 1 < NT) stage(1, U + 1, 1); }
            else if (p == 2) { if (U + 2 < NT) stage(1, U + 2, 0); }
            else             { if (U + 2 < NT) stage(0, U + 2, 0); }
            asm volatile("" ::: "memory");
            __builtin_amdgcn_s_barrier();
            asm volatile("" ::: "memory");
            __builtin_amdgcn_s_setprio(1);
#pragma unroll
            for (int kk = 0; kk < 2; ++kk)
#pragma unroll
                for (int m = 0; m < 4; ++m)
#pragma unroll
                    for (int n = 0; n < 2; ++n)
                        acc[p][m][n] = __builtin_amdgcn_mfma_f32_16x16x32_bf16(
                            a[m][kk], b[n][kk], acc[p][m][n], 0, 0, 0);
            __builtin_amdgcn_s_setprio(0);
            if (p == 3) asm volatile("s_waitcnt vmcnt(4)" ::: "memory");
            asm volatile("" ::: "memory");
            __builtin_amdgcn_s_barrier();
            asm volatile("" ::: "memory");
        }
    }

    // ---- epilogue ----
#pragma unroll
    for (int p = 0; p < 4; ++p) {
        const int rb = row0 + (p & 1) * 128 + wy * 64 + (lane >> 4) * 4;
        const int cb = col0 + (p >> 1) * 128 + wx * 32 + (lane & 15);
#pragma unroll
        for (int n = 0; n < 2; ++n) {
            const float bv = bias[cb + n * 16];
#pragma unroll
            for (int m = 0; m < 4; ++m) {
#pragma unroll
                for (int r = 0; r < 4; ++r) {
                    const float v = acc[p][m][n][r] + bv;
                    const size_t off = (size_t)(rb + m * 16 + r) * ldc + cb + n * 16;
                    if (OUT_BF16) ((ushort*)Cout)[off] = f2b(v);
                    else          ((float*)Cout)[off]  = v;
                }
            }
        }
    }
}

// ---------------------------------------------------------------------------
// transpose + convert: out[C][R] bf16 = in[R][C] fp32   (R,C multiples of 32)
// ---------------------------------------------------------------------------
__global__ __launch_bounds__(256)
void transpose_to_bf16(const float* __restrict__ in, ushort* __restrict__ out,
                       int R, int C)
{
    __shared__ float t[32][33];
    const int c0 = blockIdx.x * 32, r0 = blockIdx.y * 32;
    const int tx = threadIdx.x & 31, ty = threadIdx.x >> 5;   // 32 x 8
#pragma unroll
    for (int i = 0; i < 32; i += 8)
        t[ty + i][tx] = in[(size_t)(r0 + ty + i) * C + c0 + tx];
    __syncthreads();
#pragma unroll
    for (int i = 0; i < 32; i += 8)
        out[(size_t)(c0 + ty + i) * R + r0 + tx] = f2b(t[tx][ty + i]);
}

// elementwise fp32 -> bf16 (n divisible by 1024)
__global__ __launch_bounds__(256)
void conv_bf16(const float* __restrict__ in, ushort* __restrict__ out)
{
    const int i = blockIdx.x * 256 + threadIdx.x;
    float4 v = ((const float4*)in)[i];
    ushort4 o;
    o.x = f2b(v.x); o.y = f2b(v.y); o.z = f2b(v.z); o.w = f2b(v.w);
    ((ushort4*)out)[i] = o;
}

// concat two [Mm] bias vectors into one [2*Mm]
__global__ __launch_bounds__(256)
void concat2(const float* __restrict__ a, const float* __restrict__ b,
             float* __restrict__ o)
{
    const int i = blockIdx.x * 256 + threadIdx.x;
    o[i] = (i < Mm) ? a[i] : b[i - Mm];
}

// ---------------------------------------------------------------------------
// Split-K fp32 GEMM: partials P[zz][Mrows][Ncols], zz = batch*SPLITK + ks.
// ---------------------------------------------------------------------------
template<int BM, int BN, int BK, int TM, int TN, int SPLITK>
__global__ __launch_bounds__(256)
void gemm_f32_sk(const float* __restrict__ A, int lda, long long sA,
                 const float* __restrict__ B, int ldb, long long sB,
                 float* __restrict__ P, int Mrows, int Ncols, int Kdim)
{
    constexpr int TX = BN / TN;
    constexpr int TY = BM / TM;
    static_assert(TX * TY == 256, "256 threads");
    constexpr int KC4   = BK / 4;
    constexpr int A_PER = (BM * BK / 4) / 256;
    constexpr int B_PER = (BK * BN / 4) / 256;

    __shared__ float As[BK][BM + 4];
    __shared__ float Bs[BK][BN];

    const int tid = threadIdx.x;
    const int tx  = tid % TX;
    const int ty  = tid / TX;
    const int zz  = blockIdx.z;
    const int zb  = zz / SPLITK;
    const int ks  = zz % SPLITK;
    A += (long long)zb * sA;
    B += (long long)zb * sB;
    const int Kslice = Kdim / SPLITK;
    const int kbeg = ks * Kslice, kend = kbeg + Kslice;
    const int row0 = blockIdx.y * BM;
    const int col0 = blockIdx.x * BN;

    float acc[TM][TN];
#pragma unroll
    for (int i = 0; i < TM; ++i)
#pragma unroll
        for (int j = 0; j < TN; ++j) acc[i][j] = 0.f;

    for (int k0 = kbeg; k0 < kend; k0 += BK) {
        __syncthreads();
#pragma unroll
        for (int l = 0; l < A_PER; ++l) {
            int idx = tid + l * 256;
            int ar  = idx / KC4;
            int ac  = (idx % KC4) * 4;
            float4 va = *(const float4*)&A[(long long)(row0 + ar) * lda + k0 + ac];
            As[ac + 0][ar] = va.x;
            As[ac + 1][ar] = va.y;
            As[ac + 2][ar] = va.z;
            As[ac + 3][ar] = va.w;
        }
#pragma unroll
        for (int l = 0; l < B_PER; ++l) {
            int idx = tid + l * 256;
            int br  = idx / (BN / 4);
            int bc  = (idx % (BN / 4)) * 4;
            *(float4*)&Bs[br][bc] = *(const float4*)&B[(long long)(k0 + br) * ldb + col0 + bc];
        }
        __syncthreads();
#pragma unroll
        for (int k = 0; k < BK; ++k) {
            float a[TM], b[TN];
#pragma unroll
            for (int i = 0; i < TM; i += 4)
                *(float4*)&a[i] = *(const float4*)&As[k][ty * TM + i];
#pragma unroll
            for (int j = 0; j < TN; j += 4)
                *(float4*)&b[j] = *(const float4*)&Bs[k][tx * TN + j];
#pragma unroll
            for (int i = 0; i < TM; ++i)
#pragma unroll
                for (int j = 0; j < TN; ++j)
                    acc[i][j] = fmaf(a[i], b[j], acc[i][j]);
        }
    }

    float* Pz = P + (size_t)zz * Mrows * Ncols;
#pragma unroll
    for (int i = 0; i < TM; ++i) {
        const size_t prow = (size_t)(row0 + ty * TM + i) * Ncols;
#pragma unroll
        for (int j = 0; j < TN; j += 4)
            *(float4*)&Pz[prow + col0 + tx * TN + j] = *(const float4*)&acc[i][j];
    }
}

// ---------------------------------------------------------------------------
// sk_reduce: C[batch][row][col] = (relu?)( sum_ks P + bias[batch][col] )
// ---------------------------------------------------------------------------
template<int SPLITK, bool RELU>
__global__ __launch_bounds__(256)
void sk_reduce(const float* __restrict__ P, const float* __restrict__ bias,
               long long sBias, float* __restrict__ C, int ldc, long long sC,
               int pb4, int Ncols)
{
    const int gid = blockIdx.x * 256 + threadIdx.x;
    const int batch = gid / pb4;
    const int r4    = gid % pb4;
    const float4* Pb = (const float4*)P + (size_t)batch * SPLITK * pb4 + r4;
    float4 s = Pb[0];
#pragma unroll
    for (int ks = 1; ks < SPLITK; ++ks) {
        float4 p = Pb[(size_t)ks * pb4];
        s.x += p.x; s.y += p.y; s.z += p.z; s.w += p.w;
    }
    const int col = (r4 * 4) % Ncols;
    const int row = (r4 * 4) / Ncols;
    float4 bv = *(const float4*)&bias[batch * sBias + col];
    s.x += bv.x; s.y += bv.y; s.z += bv.z; s.w += bv.w;
    if (RELU) {
        s.x = fmaxf(s.x, 0.f); s.y = fmaxf(s.y, 0.f);
        s.z = fmaxf(s.z, 0.f); s.w = fmaxf(s.w, 0.f);
    }
    *(float4*)&C[(size_t)batch * sC + (size_t)row * ldc + col] = s;
}

// ---------------------------------------------------------------------------
// gi_mean[b, m] = (1/T) * sum_t relu(rl_w[m] * x_bf16[b, t, m])
// ---------------------------------------------------------------------------
__global__ __launch_bounds__(256)
void gi_reduce(const ushort* __restrict__ x, const float* __restrict__ rl_w,
               float* __restrict__ gi_mean)
{
    const int b    = blockIdx.x / (Mm / 256);
    const int mblk = blockIdx.x % (Mm / 256);
    const int m    = mblk * 256 + threadIdx.x;
    const float w  = rl_w[m];
    const ushort* xp = x + (size_t)b * Tt * Mm + m;
    float sum = 0.f;
    for (int t = 0; t < Tt; ++t)
        sum += fmaxf(w * b2f(xp[(size_t)t * Mm]), 0.f);
    gi_mean[b * Mm + m] = sum * (1.f / (float)Tt);
}

// ---------------------------------------------------------------------------
// Fused attention per (b, h): q fp32 [.,S,M]; kv bf16 [.,T,2M]
// ---------------------------------------------------------------------------
__global__ __launch_bounds__(256)
void attn_kernel(const float* __restrict__ q, const ushort* __restrict__ kv,
                 float* __restrict__ att)
{
    const int b = blockIdx.x / Hh;
    const int h = blockIdx.x % Hh;
    const int tid = threadIdx.x;

    __shared__ float qs[Ss][KDd];
    __shared__ float sc[Ss][Tt];

    {
        int s  = tid / 32;
        int d4 = (tid % 32) * 4;
        float4 qv = *(const float4*)&q[((size_t)(b * Ss + s)) * Mm + h * KDd + d4];
        qs[s][d4 + 0] = qv.x; qs[s][d4 + 1] = qv.y;
        qs[s][d4 + 2] = qv.z; qs[s][d4 + 3] = qv.w;
    }
    __syncthreads();

#pragma unroll
    for (int half = 0; half < 2; ++half) {
        const int t = tid + half * 256;
        const ushort* kr = kv + ((size_t)(b * Tt + t)) * (2 * Mm) + h * KDd;
        float acc[Ss];
#pragma unroll
        for (int s = 0; s < Ss; ++s) acc[s] = 0.f;
        for (int d = 0; d < KDd; d += 8) {
            uint4 u = *(const uint4*)(kr + d);
            float k0 = blo(u.x), k1 = bhi(u.x), k2 = blo(u.y), k3 = bhi(u.y);
            float k4 = blo(u.z), k5 = bhi(u.z), k6 = blo(u.w), k7 = bhi(u.w);
#pragma unroll
            for (int s = 0; s < Ss; ++s)
                acc[s] += qs[s][d + 0] * k0 + qs[s][d + 1] * k1
                        + qs[s][d + 2] * k2 + qs[s][d + 3] * k3
                        + qs[s][d + 4] * k4 + qs[s][d + 5] * k5
                        + qs[s][d + 6] * k6 + qs[s][d + 7] * k7;
        }
#pragma unroll
        for (int s = 0; s < Ss; ++s) sc[s][t] = acc[s];
    }
    __syncthreads();

    const int s    = tid >> 5;
    const int lane = tid & 31;
    float mx = -1e30f;
    for (int t = lane; t < Tt; t += 32) mx = fmaxf(mx, sc[s][t]);
#pragma unroll
    for (int m = 16; m >= 1; m >>= 1) mx = fmaxf(mx, __shfl_xor(mx, m));
    float sum = 0.f;
    for (int t = lane; t < Tt; t += 32) {
        float e = __expf(sc[s][t] - mx);
        sc[s][t] = e;
        sum += e;
    }
#pragma unroll
    for (int m = 16; m >= 1; m >>= 1) sum += __shfl_xor(sum, m);
    const float inv = 1.f / sum;
    __syncthreads();

    const int d0 = (tid & 31) * 4;
    const ushort* vb = kv + ((size_t)(b * Tt)) * (2 * Mm) + Mm + h * KDd + d0;
    float4 acc = make_float4(0.f, 0.f, 0.f, 0.f);
    for (int t = 0; t < Tt; ++t) {
        const float p = sc[s][t];
        uint2 u = *(const uint2*)(vb + (size_t)t * (2 * Mm));
        acc.x = fmaf(p, blo(u.x), acc.x);
        acc.y = fmaf(p, bhi(u.x), acc.y);
        acc.z = fmaf(p, blo(u.y), acc.z);
        acc.w = fmaf(p, bhi(u.y), acc.w);
    }
    float4 o = make_float4(acc.x * inv, acc.y * inv, acc.z * inv, acc.w * inv);
    *(float4*)&att[((size_t)(b * Ss + s)) * Mm + h * KDd + d0] = o;
}

// ---------------------------------------------------------------------------
__global__ __launch_bounds__(256)
void ln_add(const float* __restrict__ a, const float* __restrict__ b,
            const float* __restrict__ g, const float* __restrict__ be,
            float* __restrict__ out)
{
    const int row = blockIdx.x;
    const int tid = threadIdx.x;
    const float* ap = a + (size_t)row * Mm;
    const float* bp = b + (size_t)row * Mm;

    float4 av = *(const float4*)&ap[tid * 4];
    float4 bv = *(const float4*)&bp[tid * 4];
    float x0 = av.x + bv.x, x1 = av.y + bv.y, x2 = av.z + bv.z, x3 = av.w + bv.w;
    float s  = x0 + x1 + x2 + x3;
    float ss = x0 * x0 + x1 * x1 + x2 * x2 + x3 * x3;
#pragma unroll
    for (int m = 32; m >= 1; m >>= 1) {
        s  += __shfl_xor(s, m);
        ss += __shfl_xor(ss, m);
    }
    __shared__ float red[2][4];
    const int wid = tid >> 6;
    if ((tid & 63) == 0) { red[0][wid] = s; red[1][wid] = ss; }
    __syncthreads();
    s  = red[0][0] + red[0][1] + red[0][2] + red[0][3];
    ss = red[1][0] + red[1][1] + red[1][2] + red[1][3];
    const float mu  = s * (1.f / (float)Mm);
    const float var = ss * (1.f / (float)Mm) - mu * mu;
    const float inv = rsqrtf(var + 1e-5f);

    float4 gv = *(const float4*)&g[tid * 4];
    float4 bev = *(const float4*)&be[tid * 4];
    float4 o;
    o.x = (x0 - mu) * inv * gv.x + bev.x;
    o.y = (x1 - mu) * inv * gv.y + bev.y;
    o.z = (x2 - mu) * inv * gv.z + bev.z;
    o.w = (x3 - mu) * inv * gv.w + bev.w;
    *(float4*)&out[(size_t)row * Mm + tid * 4] = o;
}

__global__ __launch_bounds__(256)
void tanh_kernel(const float* __restrict__ in, float* __restrict__ out)
{
    const int idx = blockIdx.x * 256 + threadIdx.x;
    out[idx] = tanhf(in[idx]);
}

__global__ __launch_bounds__(256)
void combine_kernel(const float* __restrict__ gm, const float* __restrict__ gi,
                    const float* __restrict__ nextm, const float* __restrict__ memory,
                    const float* __restrict__ ibp, const float* __restrict__ fbp,
                    float* __restrict__ out)
{
    const int idx = blockIdx.x * 256 + threadIdx.x;
    const int m  = idx & (Mm - 1);
    const int bs = idx >> 10;
    const int b  = bs >> 3;
    const float ib = ibp[0], fb = fbp[0];
    const float gmi = gm[(size_t)bs * NGg + m];
    const float gmf = gm[(size_t)bs * NGg + Mm + m];
    const float gii = gi[(size_t)b * NGg + m];
    const float gif = gi[(size_t)b * NGg + Mm + m];
    const float ig = 1.f / (1.f + __expf(-(gmi + gii + ib)));
    const float fg = 1.f / (1.f + __expf(-(gmf + gif + fb)));
    out[idx] = ig * tanhf(nextm[idx]) + fg * memory[idx];
}

// ---------------------------------------------------------------------------
extern "C" void kernel_launch(void* const* d_in, const int* in_sizes, int n_in,
                              void* d_out, int out_size, void* d_ws, size_t ws_size,
                              hipStream_t stream)
{
    const float* inputs = (const float*)d_in[0];
    const float* memory = (const float*)d_in[1];
    const float* Wp  = (const float*)d_in[2];
    const float* bp  = (const float*)d_in[3];
    const float* Wq  = (const float*)d_in[4];
    const float* bq  = (const float*)d_in[5];
    const float* Wk  = (const float*)d_in[6];
    const float* bk  = (const float*)d_in[7];
    const float* Wv  = (const float*)d_in[8];
    const float* bv  = (const float*)d_in[9];
    const float* Wm  = (const float*)d_in[10];
    const float* bm  = (const float*)d_in[11];
    const float* g1  = (const float*)d_in[12];
    const float* be1 = (const float*)d_in[13];
    const float* g2  = (const float*)d_in[14];
    const float* be2 = (const float*)d_in[15];
    const float* rl_w = (const float*)d_in[16];
    const float* rl_W = (const float*)d_in[17];
    const float* rl_b = (const float*)d_in[18];
    const float* gl_W = (const float*)d_in[19];
    const float* gl_b = (const float*)d_in[20];
    const float* ibp  = (const float*)d_in[21];
    const float* fbp  = (const float*)d_in[22];
    float* out = (float*)d_out;

    // allow 128 KiB dynamic LDS for the 8-phase GEMM
    (void)hipFuncSetAttribute(reinterpret_cast<const void*>(&gemm_8ph<1>),
                              hipFuncAttributeMaxDynamicSharedMemorySize, 131072);

    // ---- workspace layout (float units) ----
    const size_t N_SM = (size_t)Bq * Ss * Mm;     // 524,288
    float* ws = (float*)d_ws;
    float* qbuf   = ws;
    float* attb   = qbuf   + N_SM;
    float* mem1   = attb   + N_SM;
    float* mlp1   = mem1   + N_SM;
    float* mlp2   = mlp1   + N_SM;
    float* nextm  = mlp2   + N_SM;
    float* tm     = nextm  + N_SM;
    float* gimean = tm     + N_SM;
    float* gibuf  = gimean + (size_t)Bq * Mm;
    float* gmbuf  = gibuf  + (size_t)Bq * NGg;
    float* skp    = gmbuf  + (size_t)Bq * Ss * NGg;       // split-K partials
    const size_t SKP_FLOATS = (size_t)8 * 512 * 1024;     // 4.19M floats (max use)
    float* bkv    = skp + SKP_FLOATS;                     // [2048] concat bias
    float* pconst = bkv + NGg;
    // bf16 constants
    ushort* ib16 = (ushort*)pconst;                       // [B*T][DIN]
    ushort* WpT  = ib16 + (size_t)Bq * Tt * DIN;          // [M][DIN]
    ushort* WkvT = WpT  + (size_t)Mm * DIN;               // [2M][M]: WkT then WvT
    ushort* cend = WkvT + (size_t)2 * Mm * Mm;
    // chunk region start (float*, 16B aligned)
    size_t const_u16 = (size_t)(cend - (ushort*)pconst);
    size_t const_floats = (size_t)(pconst - ws) + (const_u16 + 1) / 2;
    const_floats = (const_floats + 3) & ~(size_t)3;       // 16B align
    float* cstart = ws + const_floats;

    // per-chunk: kv bf16 (Bc*T*2M u16) + xb16 (Bc*T*M u16)
    int Bc = Bq;
    while (Bc > 1 &&
           (const_floats + (size_t)Bc * Tt * Mm * 3 / 2) * sizeof(float) > ws_size)
        Bc >>= 1;
    const size_t N_XC = (size_t)Bc * Tt * Mm;
    ushort* kvb16 = (ushort*)cstart;                      // [Bc*T][2M]
    ushort* xb16  = kvb16 + 2 * N_XC;                     // [Bc*T][M]

    const dim3 blk(256);

    // ---- precompute bf16 operands + concat bias ----
    conv_bf16<<<dim3((Bq * Tt * DIN) / 1024), blk, 0, stream>>>(inputs, ib16);
    transpose_to_bf16<<<dim3(Mm / 32, DIN / 32), blk, 0, stream>>>(Wp, WpT, DIN, Mm);
    transpose_to_bf16<<<dim3(Mm / 32, Mm / 32), blk, 0, stream>>>(Wk, WkvT, Mm, Mm);
    transpose_to_bf16<<<dim3(Mm / 32, Mm / 32), blk, 0, stream>>>(Wv, WkvT + (size_t)Mm * Mm, Mm, Mm);
    concat2<<<dim3(NGg / 256), blk, 0, stream>>>(bk, bv, bkv);

    // q = memory @ Wq + bq   (split-K=8)
    gemm_f32_sk<64,64,16,4,4,8><<<dim3(Mm/64, (Bq*Ss)/64, 8), blk, 0, stream>>>(
        memory, Mm, 0, Wq, Mm, 0, skp, Bq*Ss, Mm, Mm);
    sk_reduce<8,false><<<dim3((Bq*Ss*Mm)/1024), blk, 0, stream>>>(
        skp, bq, 0, qbuf, Mm, 0, (Bq*Ss*Mm)/4, Mm);

    // ---- chunked: x(bf16), kv(bf16), gi_reduce, attention ----
    for (int c0 = 0; c0 < Bq; c0 += Bc) {
        const int rows = Bc * Tt;

        // x_bf16 = bf16(inputs_c @ Wp + bp)   (8-phase MFMA)
        gemm_8ph<1><<<dim3(Mm/256, rows/256), dim3(512), 131072, stream>>>(
            ib16 + (size_t)c0 * Tt * DIN, WpT, bp, xb16, Mm, DIN);

        // kv = bf16(x @ [Wk|Wv] + [bk|bv])    (8-phase MFMA, N=2048)
        gemm_8ph<1><<<dim3((2*Mm)/256, rows/256), dim3(512), 131072, stream>>>(
            xb16, WkvT, bkv, kvb16, 2*Mm, Mm);

        // gi_mean_c = mean_t relu(rl_w * x)
        gi_reduce<<<dim3(Bc * (Mm/256)), blk, 0, stream>>>(
            xb16, rl_w, gimean + (size_t)c0 * Mm);

        // attention for this chunk
        attn_kernel<<<dim3(Bc * Hh), blk, 0, stream>>>(
            qbuf + (size_t)c0 * Ss * Mm, kvb16,
            attb + (size_t)c0 * Ss * Mm);
    }

    // mem1 = LN(memory + att)
    ln_add<<<dim3(Bq * Ss), blk, 0, stream>>>(memory, attb, g1, be1, mem1);

    // mlp1 = relu(mem1 @ Wm + bm)   (split-K=8)
    gemm_f32_sk<64,64,16,4,4,8><<<dim3(Mm/64, (Bq*Ss)/64, 8), blk, 0, stream>>>(
        mem1, Mm, 0, Wm, Mm, 0, skp, Bq*Ss, Mm, Mm);
    sk_reduce<8,true><<<dim3((Bq*Ss*Mm)/1024), blk, 0, stream>>>(
        skp, bm, 0, mlp1, Mm, 0, (Bq*Ss*Mm)/4, Mm);

    // mlp2 = relu(mlp1 @ Wm + bm)
    gemm_f32_sk<64,64,16,4,4,8><<<dim3(Mm/64, (Bq*Ss)/64, 8), blk, 0, stream>>>(
        mlp1, Mm, 0, Wm, Mm, 0, skp, Bq*Ss, Mm, Mm);
    sk_reduce<8,true><<<dim3((Bq*Ss*Mm)/1024), blk, 0, stream>>>(
        skp, bm, 0, mlp2, Mm, 0, (Bq*Ss*Mm)/4, Mm);

    // next = LN(mem1 + mlp2)
    ln_add<<<dim3(Bq * Ss), blk, 0, stream>>>(mem1, mlp2, g2, be2, nextm);

    // tm = tanh(memory)
    tanh_kernel<<<dim3((Bq*Ss*Mm)/256), blk, 0, stream>>>(memory, tm);

    // gm[:, s, :] = tm[:, s, :] @ gl_W[s] + gl_b[s]   (batch z=8, split-K=4)
    gemm_f32_sk<64,64,16,4,4,4><<<dim3(NGg/64, Bq/64, Ss*4), blk, 0, stream>>>(
        tm, Ss*Mm, (long long)Mm,
        gl_W, NGg, (long long)Mm * NGg,
        skp, Bq, NGg, Mm);
    sk_reduce<4,false><<<dim3((Ss*Bq*NGg)/1024), blk, 0, stream>>>(
        skp, gl_b, NGg, gmbuf, Ss*NGg, NGg, (Bq*NGg)/4, NGg);

    // gi = gi_mean @ rl_W + rl_b   (split-K=8)
    gemm_f32_sk<64,64,16,4,4,8><<<dim3(NGg/64, Bq/64, 8), blk, 0, stream>>>(
        gimean, Mm, 0, rl_W, NGg, 0, skp, Bq, NGg, Mm);
    sk_reduce<8,false><<<dim3((Bq*NGg)/1024), blk, 0, stream>>>(
        skp, rl_b, 0, gibuf, NGg, 0, (Bq*NGg)/4, NGg);

    // final gates + output
    combine_kernel<<<dim3((Bq*Ss*Mm)/256), blk, 0, stream>>>(
        gmbuf, gibuf, nextm, memory, ibp, fbp, out);
}

// Round 8
// 502.447 us; speedup vs baseline: 4.7261x; 1.0272x over previous
//
#include <hip/hip_runtime.h>
#include <hip/hip_bf16.h>

// Problem constants
#define Bq   64
#define Tt   512
#define DIN  512
#define Ss   8
#define HSs  128
#define Hh   8
#define Mm   1024
#define KDd  128
#define NGg  2048

typedef __attribute__((ext_vector_type(8))) short bf16x8;
typedef __attribute__((ext_vector_type(4))) float f32x4;

__device__ __forceinline__ ushort f2b(float f) {
    union { float f; unsigned u; } v; v.f = f;
    unsigned r = v.u + 0x7fffu + ((v.u >> 16) & 1u);   // RNE
    return (ushort)(r >> 16);
}
__device__ __forceinline__ float b2f(ushort b) {
    union { unsigned u; float f; } v; v.u = ((unsigned)b) << 16;
    return v.f;
}
__device__ __forceinline__ float blo(unsigned u) {
    union { unsigned u; float f; } v; v.u = u << 16; return v.f;
}
__device__ __forceinline__ float bhi(unsigned u) {
    union { unsigned u; float f; } v; v.u = u & 0xffff0000u; return v.f;
}

#define GLOAD_LDS16(g, l) __builtin_amdgcn_global_load_lds( \
    (const __attribute__((address_space(1))) void*)(g),     \
    (__attribute__((address_space(3))) void*)(l), 16, 0, 0)

// ---------------------------------------------------------------------------
// 256x256 bf16 MFMA GEMM, BK=64, 512 threads (8 waves as 2x4), K-tile
// fragments held fully in registers (24 ds_read_b128/wave/tile — minimal).
// LDS 128 KiB: A/B regions, each 2 bufs x 2 half-tiles x (128 x 64bf16).
// Per tile U: {24 ds_read (buf U&1) -> lgkmcnt(0) -> barrier ->
//   stage tile U+2 into buf U&1 (safe: all waves done reading) ->
//   64 MFMA (setprio) -> vmcnt(8) [vmcnt(0) at tail] -> barrier}.
// Counted vmcnt: 16 loads in flight after stage, drain 8 oldest (= tile U+1's)
// at tile end; end barrier = collective drain (each wave stages its own slice).
// T2 swizzle: LDS slot (row r, 16B-slot q) holds k-slot q^(r&7) via
// pre-swizzled global source + same XOR on read (both-sides involution).
// T1 bijective XCD swizzle on block indices.
// A [rows][K] bf16; Bt [N][K] bf16; bias fp32 [N]; C bf16 or fp32.
// Requires: rows%256==0, N%256==0, K%64==0, K/64 >= 2.
// ---------------------------------------------------------------------------
template<int OUT_BF16>
__global__ __launch_bounds__(512)
void gemm_8ph(const ushort* __restrict__ A, const ushort* __restrict__ Bt,
              const float* __restrict__ bias, void* __restrict__ Cout,
              int ldc, int Kdim)
{
    extern __shared__ __align__(16) char lds[];   // 131072 bytes

    const int tid  = threadIdx.x;
    const int wid  = tid >> 6;
    const int lane = tid & 63;
    const int wy   = wid >> 2;          // 0..1: row 64-block within 128-piece
    const int wx   = wid & 3;           // 0..3: col 32-block within 128-piece

    // ---- bijective XCD swizzle (T1, m204) ----
    const int gx   = gridDim.x;
    const int nwg  = gx * gridDim.y;
    const int orig = blockIdx.y * gx + blockIdx.x;
    const int q8   = nwg >> 3, r8 = nwg & 7;
    const int xcd  = orig & 7, idx8 = orig >> 3;
    const int swz  = (xcd < r8 ? xcd * (q8 + 1)
                               : r8 * (q8 + 1) + (xcd - r8) * q8) + idx8;
    const int row0 = (swz / gx) * 256;
    const int col0 = (swz % gx) * 256;

    const int NT = Kdim >> 6;

    // ---- staging source (pre-swizzled global address; LDS dest linear) ----
    const int sr = tid >> 3;
    const int sq = (tid & 7) ^ (sr & 7);
    const ushort* Asrc = A  + (size_t)(row0 + sr) * Kdim + sq * 8;
    const ushort* Bsrc = Bt + (size_t)(col0 + sr) * Kdim + sq * 8;
    const int ldsw = wid * 1024;        // wave-uniform LDS offset

    auto stage = [&](int isB, int U, int h) {
        const ushort* s = (isB ? Bsrc : Asrc) + (size_t)h * 128 * Kdim
                        + (size_t)U * 64;
        char* d = lds + (isB ? 65536 : 0) + ((((U) & 1) * 2 + h) << 14) + ldsw;
        GLOAD_LDS16(s, d);
        GLOAD_LDS16(s + (size_t)64 * Kdim, d + 8192);
    };
    auto stage_tile = [&](int U) {
        stage(0, U, 0); stage(0, U, 1); stage(1, U, 0); stage(1, U, 1);
    };

    // ---- read-side swizzled lane offsets ----
    const int l15   = lane & 15;
    const int s0_16 = (((lane >> 4)) ^ (lane & 7)) << 4;        // kk=0 slot*16
    const int s1_16 = ((4 + (lane >> 4)) ^ (lane & 7)) << 4;    // kk=1 slot*16
    const int aoff  = wy * 8192 + l15 * 128;
    const int boff  = wx * 4096 + l15 * 128;

    f32x4 acc[4][4][2];
#pragma unroll
    for (int p = 0; p < 4; ++p)
#pragma unroll
        for (int m = 0; m < 4; ++m)
#pragma unroll
            for (int n = 0; n < 2; ++n) acc[p][m][n] = (f32x4){0.f,0.f,0.f,0.f};

    // ---- prologue: stage tiles 0 and 1; wait for tile 0 ----
    stage_tile(0);
    stage_tile(1);
    asm volatile("s_waitcnt vmcnt(8)" ::: "memory");
    __builtin_amdgcn_s_barrier();
    asm volatile("" ::: "memory");

    for (int U = 0; U < NT; ++U) {
        const char* Ab = lds + ((U & 1) << 15);
        const char* Bb = lds + 65536 + ((U & 1) << 15);

        // ---- read ALL fragments for this K-tile into registers (24 b128) ----
        bf16x8 a[2][2][4];   // [kk][ha][m]
        bf16x8 b[2][2][2];   // [kk][hb][n]
#pragma unroll
        for (int ha = 0; ha < 2; ++ha)
#pragma unroll
            for (int m = 0; m < 4; ++m) {
                a[0][ha][m] = *(const bf16x8*)(Ab + (ha << 14) + aoff + s0_16 + m * 2048);
                a[1][ha][m] = *(const bf16x8*)(Ab + (ha << 14) + aoff + s1_16 + m * 2048);
            }
#pragma unroll
        for (int hb = 0; hb < 2; ++hb)
#pragma unroll
            for (int n = 0; n < 2; ++n) {
                b[0][hb][n] = *(const bf16x8*)(Bb + (hb << 14) + boff + s0_16 + n * 2048);
                b[1][hb][n] = *(const bf16x8*)(Bb + (hb << 14) + boff + s1_16 + n * 2048);
            }
        asm volatile("s_waitcnt lgkmcnt(0)" ::: "memory");   // reads landed
        __builtin_amdgcn_s_barrier();                         // all waves done
        asm volatile("" ::: "memory");

        // stage tile U+2 into the buffer just freed (same parity as U)
        if (U + 2 < NT) stage_tile(U + 2);

        __builtin_amdgcn_s_setprio(1);
#pragma unroll
        for (int kk = 0; kk < 2; ++kk)
#pragma unroll
            for (int ha = 0; ha < 2; ++ha)
#pragma unroll
                for (int hb = 0; hb < 2; ++hb)
#pragma unroll
                    for (int m = 0; m < 4; ++m)
#pragma unroll
                        for (int n = 0; n < 2; ++n)
                            acc[hb * 2 + ha][m][n] =
                                __builtin_amdgcn_mfma_f32_16x16x32_bf16(
                                    a[kk][ha][m], b[kk][hb][n],
                                    acc[hb * 2 + ha][m][n], 0, 0, 0);
        __builtin_amdgcn_s_setprio(0);

        // drain tile U+1's loads (counted; only full-drain at the tail)
        if (U + 2 < NT) asm volatile("s_waitcnt vmcnt(8)" ::: "memory");
        else            asm volatile("s_waitcnt vmcnt(0)" ::: "memory");
        __builtin_amdgcn_s_barrier();                         // collective drain
        asm volatile("" ::: "memory");
    }

    // ---- epilogue: p&1 = row half (ha), p>>1 = col half (hb) ----
#pragma unroll
    for (int p = 0; p < 4; ++p) {
        const int rb = row0 + (p & 1) * 128 + wy * 64 + (lane >> 4) * 4;
        const int cb = col0 + (p >> 1) * 128 + wx * 32 + (lane & 15);
#pragma unroll
        for (int n = 0; n < 2; ++n) {
            const float bv = bias[cb + n * 16];
#pragma unroll
            for (int m = 0; m < 4; ++m) {
#pragma unroll
                for (int r = 0; r < 4; ++r) {
                    const float v = acc[p][m][n][r] + bv;
                    const size_t off = (size_t)(rb + m * 16 + r) * ldc + cb + n * 16;
                    if (OUT_BF16) ((ushort*)Cout)[off] = f2b(v);
                    else          ((float*)Cout)[off]  = v;
                }
            }
        }
    }
}

// ---------------------------------------------------------------------------
// transpose + convert: out[C][R] bf16 = in[R][C] fp32   (R,C multiples of 32)
// ---------------------------------------------------------------------------
__global__ __launch_bounds__(256)
void transpose_to_bf16(const float* __restrict__ in, ushort* __restrict__ out,
                       int R, int C)
{
    __shared__ float t[32][33];
    const int c0 = blockIdx.x * 32, r0 = blockIdx.y * 32;
    const int tx = threadIdx.x & 31, ty = threadIdx.x >> 5;   // 32 x 8
#pragma unroll
    for (int i = 0; i < 32; i += 8)
        t[ty + i][tx] = in[(size_t)(r0 + ty + i) * C + c0 + tx];
    __syncthreads();
#pragma unroll
    for (int i = 0; i < 32; i += 8)
        out[(size_t)(c0 + ty + i) * R + r0 + tx] = f2b(t[tx][ty + i]);
}

// elementwise fp32 -> bf16 (n divisible by 1024)
__global__ __launch_bounds__(256)
void conv_bf16(const float* __restrict__ in, ushort* __restrict__ out)
{
    const int i = blockIdx.x * 256 + threadIdx.x;
    float4 v = ((const float4*)in)[i];
    ushort4 o;
    o.x = f2b(v.x); o.y = f2b(v.y); o.z = f2b(v.z); o.w = f2b(v.w);
    ((ushort4*)out)[i] = o;
}

// concat two [Mm] bias vectors into one [2*Mm]
__global__ __launch_bounds__(256)
void concat2(const float* __restrict__ a, const float* __restrict__ b,
             float* __restrict__ o)
{
    const int i = blockIdx.x * 256 + threadIdx.x;
    o[i] = (i < Mm) ? a[i] : b[i - Mm];
}

// ---------------------------------------------------------------------------
// Split-K fp32 GEMM: partials P[zz][Mrows][Ncols], zz = batch*SPLITK + ks.
// ---------------------------------------------------------------------------
template<int BM, int BN, int BK, int TM, int TN, int SPLITK>
__global__ __launch_bounds__(256)
void gemm_f32_sk(const float* __restrict__ A, int lda, long long sA,
                 const float* __restrict__ B, int ldb, long long sB,
                 float* __restrict__ P, int Mrows, int Ncols, int Kdim)
{
    constexpr int TX = BN / TN;
    constexpr int TY = BM / TM;
    static_assert(TX * TY == 256, "256 threads");
    constexpr int KC4   = BK / 4;
    constexpr int A_PER = (BM * BK / 4) / 256;
    constexpr int B_PER = (BK * BN / 4) / 256;

    __shared__ float As[BK][BM + 4];
    __shared__ float Bs[BK][BN];

    const int tid = threadIdx.x;
    const int tx  = tid % TX;
    const int ty  = tid / TX;
    const int zz  = blockIdx.z;
    const int zb  = zz / SPLITK;
    const int ks  = zz % SPLITK;
    A += (long long)zb * sA;
    B += (long long)zb * sB;
    const int Kslice = Kdim / SPLITK;
    const int kbeg = ks * Kslice, kend = kbeg + Kslice;
    const int row0 = blockIdx.y * BM;
    const int col0 = blockIdx.x * BN;

    float acc[TM][TN];
#pragma unroll
    for (int i = 0; i < TM; ++i)
#pragma unroll
        for (int j = 0; j < TN; ++j) acc[i][j] = 0.f;

    for (int k0 = kbeg; k0 < kend; k0 += BK) {
        __syncthreads();
#pragma unroll
        for (int l = 0; l < A_PER; ++l) {
            int idx = tid + l * 256;
            int ar  = idx / KC4;
            int ac  = (idx % KC4) * 4;
            float4 va = *(const float4*)&A[(long long)(row0 + ar) * lda + k0 + ac];
            As[ac + 0][ar] = va.x;
            As[ac + 1][ar] = va.y;
            As[ac + 2][ar] = va.z;
            As[ac + 3][ar] = va.w;
        }
#pragma unroll
        for (int l = 0; l < B_PER; ++l) {
            int idx = tid + l * 256;
            int br  = idx / (BN / 4);
            int bc  = (idx % (BN / 4)) * 4;
            *(float4*)&Bs[br][bc] = *(const float4*)&B[(long long)(k0 + br) * ldb + col0 + bc];
        }
        __syncthreads();
#pragma unroll
        for (int k = 0; k < BK; ++k) {
            float a[TM], b[TN];
#pragma unroll
            for (int i = 0; i < TM; i += 4)
                *(float4*)&a[i] = *(const float4*)&As[k][ty * TM + i];
#pragma unroll
            for (int j = 0; j < TN; j += 4)
                *(float4*)&b[j] = *(const float4*)&Bs[k][tx * TN + j];
#pragma unroll
            for (int i = 0; i < TM; ++i)
#pragma unroll
                for (int j = 0; j < TN; ++j)
                    acc[i][j] = fmaf(a[i], b[j], acc[i][j]);
        }
    }

    float* Pz = P + (size_t)zz * Mrows * Ncols;
#pragma unroll
    for (int i = 0; i < TM; ++i) {
        const size_t prow = (size_t)(row0 + ty * TM + i) * Ncols;
#pragma unroll
        for (int j = 0; j < TN; j += 4)
            *(float4*)&Pz[prow + col0 + tx * TN + j] = *(const float4*)&acc[i][j];
    }
}

// ---------------------------------------------------------------------------
// sk_reduce: C[batch][row][col] = (relu?)( sum_ks P + bias[batch][col] )
// ---------------------------------------------------------------------------
template<int SPLITK, bool RELU>
__global__ __launch_bounds__(256)
void sk_reduce(const float* __restrict__ P, const float* __restrict__ bias,
               long long sBias, float* __restrict__ C, int ldc, long long sC,
               int pb4, int Ncols)
{
    const int gid = blockIdx.x * 256 + threadIdx.x;
    const int batch = gid / pb4;
    const int r4    = gid % pb4;
    const float4* Pb = (const float4*)P + (size_t)batch * SPLITK * pb4 + r4;
    float4 s = Pb[0];
#pragma unroll
    for (int ks = 1; ks < SPLITK; ++ks) {
        float4 p = Pb[(size_t)ks * pb4];
        s.x += p.x; s.y += p.y; s.z += p.z; s.w += p.w;
    }
    const int col = (r4 * 4) % Ncols;
    const int row = (r4 * 4) / Ncols;
    float4 bv = *(const float4*)&bias[batch * sBias + col];
    s.x += bv.x; s.y += bv.y; s.z += bv.z; s.w += bv.w;
    if (RELU) {
        s.x = fmaxf(s.x, 0.f); s.y = fmaxf(s.y, 0.f);
        s.z = fmaxf(s.z, 0.f); s.w = fmaxf(s.w, 0.f);
    }
    *(float4*)&C[(size_t)batch * sC + (size_t)row * ldc + col] = s;
}

// ---------------------------------------------------------------------------
// gi_mean[b, m] = (1/T) * sum_t relu(rl_w[m] * x_bf16[b, t, m])
// ---------------------------------------------------------------------------
__global__ __launch_bounds__(256)
void gi_reduce(const ushort* __restrict__ x, const float* __restrict__ rl_w,
               float* __restrict__ gi_mean)
{
    const int b    = blockIdx.x / (Mm / 256);
    const int mblk = blockIdx.x % (Mm / 256);
    const int m    = mblk * 256 + threadIdx.x;
    const float w  = rl_w[m];
    const ushort* xp = x + (size_t)b * Tt * Mm + m;
    float sum = 0.f;
    for (int t = 0; t < Tt; ++t)
        sum += fmaxf(w * b2f(xp[(size_t)t * Mm]), 0.f);
    gi_mean[b * Mm + m] = sum * (1.f / (float)Tt);
}

// ---------------------------------------------------------------------------
// Fused attention per (b, h): q fp32 [.,S,M]; kv bf16 [.,T,2M]
// ---------------------------------------------------------------------------
__global__ __launch_bounds__(256)
void attn_kernel(const float* __restrict__ q, const ushort* __restrict__ kv,
                 float* __restrict__ att)
{
    const int b = blockIdx.x / Hh;
    const int h = blockIdx.x % Hh;
    const int tid = threadIdx.x;

    __shared__ float qs[Ss][KDd];
    __shared__ float sc[Ss][Tt];

    {
        int s  = tid / 32;
        int d4 = (tid % 32) * 4;
        float4 qv = *(const float4*)&q[((size_t)(b * Ss + s)) * Mm + h * KDd + d4];
        qs[s][d4 + 0] = qv.x; qs[s][d4 + 1] = qv.y;
        qs[s][d4 + 2] = qv.z; qs[s][d4 + 3] = qv.w;
    }
    __syncthreads();

#pragma unroll
    for (int half = 0; half < 2; ++half) {
        const int t = tid + half * 256;
        const ushort* kr = kv + ((size_t)(b * Tt + t)) * (2 * Mm) + h * KDd;
        float acc[Ss];
#pragma unroll
        for (int s = 0; s < Ss; ++s) acc[s] = 0.f;
        for (int d = 0; d < KDd; d += 8) {
            uint4 u = *(const uint4*)(kr + d);
            float k0 = blo(u.x), k1 = bhi(u.x), k2 = blo(u.y), k3 = bhi(u.y);
            float k4 = blo(u.z), k5 = bhi(u.z), k6 = blo(u.w), k7 = bhi(u.w);
#pragma unroll
            for (int s = 0; s < Ss; ++s)
                acc[s] += qs[s][d + 0] * k0 + qs[s][d + 1] * k1
                        + qs[s][d + 2] * k2 + qs[s][d + 3] * k3
                        + qs[s][d + 4] * k4 + qs[s][d + 5] * k5
                        + qs[s][d + 6] * k6 + qs[s][d + 7] * k7;
        }
#pragma unroll
        for (int s = 0; s < Ss; ++s) sc[s][t] = acc[s];
    }
    __syncthreads();

    const int s    = tid >> 5;
    const int lane = tid & 31;
    float mx = -1e30f;
    for (int t = lane; t < Tt; t += 32) mx = fmaxf(mx, sc[s][t]);
#pragma unroll
    for (int m = 16; m >= 1; m >>= 1) mx = fmaxf(mx, __shfl_xor(mx, m));
    float sum = 0.f;
    for (int t = lane; t < Tt; t += 32) {
        float e = __expf(sc[s][t] - mx);
        sc[s][t] = e;
        sum += e;
    }
#pragma unroll
    for (int m = 16; m >= 1; m >>= 1) sum += __shfl_xor(sum, m);
    const float inv = 1.f / sum;
    __syncthreads();

    const int d0 = (tid & 31) * 4;
    const ushort* vb = kv + ((size_t)(b * Tt)) * (2 * Mm) + Mm + h * KDd + d0;
    float4 acc = make_float4(0.f, 0.f, 0.f, 0.f);
    for (int t = 0; t < Tt; ++t) {
        const float p = sc[s][t];
        uint2 u = *(const uint2*)(vb + (size_t)t * (2 * Mm));
        acc.x = fmaf(p, blo(u.x), acc.x);
        acc.y = fmaf(p, bhi(u.x), acc.y);
        acc.z = fmaf(p, blo(u.y), acc.z);
        acc.w = fmaf(p, bhi(u.y), acc.w);
    }
    float4 o = make_float4(acc.x * inv, acc.y * inv, acc.z * inv, acc.w * inv);
    *(float4*)&att[((size_t)(b * Ss + s)) * Mm + h * KDd + d0] = o;
}

// ---------------------------------------------------------------------------
__global__ __launch_bounds__(256)
void ln_add(const float* __restrict__ a, const float* __restrict__ b,
            const float* __restrict__ g, const float* __restrict__ be,
            float* __restrict__ out)
{
    const int row = blockIdx.x;
    const int tid = threadIdx.x;
    const float* ap = a + (size_t)row * Mm;
    const float* bp = b + (size_t)row * Mm;

    float4 av = *(const float4*)&ap[tid * 4];
    float4 bv = *(const float4*)&bp[tid * 4];
    float x0 = av.x + bv.x, x1 = av.y + bv.y, x2 = av.z + bv.z, x3 = av.w + bv.w;
    float s  = x0 + x1 + x2 + x3;
    float ss = x0 * x0 + x1 * x1 + x2 * x2 + x3 * x3;
#pragma unroll
    for (int m = 32; m >= 1; m >>= 1) {
        s  += __shfl_xor(s, m);
        ss += __shfl_xor(ss, m);
    }
    __shared__ float red[2][4];
    const int wid = tid >> 6;
    if ((tid & 63) == 0) { red[0][wid] = s; red[1][wid] = ss; }
    __syncthreads();
    s  = red[0][0] + red[0][1] + red[0][2] + red[0][3];
    ss = red[1][0] + red[1][1] + red[1][2] + red[1][3];
    const float mu  = s * (1.f / (float)Mm);
    const float var = ss * (1.f / (float)Mm) - mu * mu;
    const float inv = rsqrtf(var + 1e-5f);

    float4 gv = *(const float4*)&g[tid * 4];
    float4 bev = *(const float4*)&be[tid * 4];
    float4 o;
    o.x = (x0 - mu) * inv * gv.x + bev.x;
    o.y = (x1 - mu) * inv * gv.y + bev.y;
    o.z = (x2 - mu) * inv * gv.z + bev.z;
    o.w = (x3 - mu) * inv * gv.w + bev.w;
    *(float4*)&out[(size_t)row * Mm + tid * 4] = o;
}

__global__ __launch_bounds__(256)
void tanh_kernel(const float* __restrict__ in, float* __restrict__ out)
{
    const int idx = blockIdx.x * 256 + threadIdx.x;
    out[idx] = tanhf(in[idx]);
}

__global__ __launch_bounds__(256)
void combine_kernel(const float* __restrict__ gm, const float* __restrict__ gi,
                    const float* __restrict__ nextm, const float* __restrict__ memory,
                    const float* __restrict__ ibp, const float* __restrict__ fbp,
                    float* __restrict__ out)
{
    const int idx = blockIdx.x * 256 + threadIdx.x;
    const int m  = idx & (Mm - 1);
    const int bs = idx >> 10;
    const int b  = bs >> 3;
    const float ib = ibp[0], fb = fbp[0];
    const float gmi = gm[(size_t)bs * NGg + m];
    const float gmf = gm[(size_t)bs * NGg + Mm + m];
    const float gii = gi[(size_t)b * NGg + m];
    const float gif = gi[(size_t)b * NGg + Mm + m];
    const float ig = 1.f / (1.f + __expf(-(gmi + gii + ib)));
    const float fg = 1.f / (1.f + __expf(-(gmf + gif + fb)));
    out[idx] = ig * tanhf(nextm[idx]) + fg * memory[idx];
}

// ---------------------------------------------------------------------------
extern "C" void kernel_launch(void* const* d_in, const int* in_sizes, int n_in,
                              void* d_out, int out_size, void* d_ws, size_t ws_size,
                              hipStream_t stream)
{
    const float* inputs = (const float*)d_in[0];
    const float* memory = (const float*)d_in[1];
    const float* Wp  = (const float*)d_in[2];
    const float* bp  = (const float*)d_in[3];
    const float* Wq  = (const float*)d_in[4];
    const float* bq  = (const float*)d_in[5];
    const float* Wk  = (const float*)d_in[6];
    const float* bk  = (const float*)d_in[7];
    const float* Wv  = (const float*)d_in[8];
    const float* bv  = (const float*)d_in[9];
    const float* Wm  = (const float*)d_in[10];
    const float* bm  = (const float*)d_in[11];
    const float* g1  = (const float*)d_in[12];
    const float* be1 = (const float*)d_in[13];
    const float* g2  = (const float*)d_in[14];
    const float* be2 = (const float*)d_in[15];
    const float* rl_w = (const float*)d_in[16];
    const float* rl_W = (const float*)d_in[17];
    const float* rl_b = (const float*)d_in[18];
    const float* gl_W = (const float*)d_in[19];
    const float* gl_b = (const float*)d_in[20];
    const float* ibp  = (const float*)d_in[21];
    const float* fbp  = (const float*)d_in[22];
    float* out = (float*)d_out;

    // allow 128 KiB dynamic LDS for the MFMA GEMM
    (void)hipFuncSetAttribute(reinterpret_cast<const void*>(&gemm_8ph<1>),
                              hipFuncAttributeMaxDynamicSharedMemorySize, 131072);

    // ---- workspace layout (float units) ----
    const size_t N_SM = (size_t)Bq * Ss * Mm;     // 524,288
    float* ws = (float*)d_ws;
    float* qbuf   = ws;
    float* attb   = qbuf   + N_SM;
    float* mem1   = attb   + N_SM;
    float* mlp1   = mem1   + N_SM;
    float* mlp2   = mlp1   + N_SM;
    float* nextm  = mlp2   + N_SM;
    float* tm     = nextm  + N_SM;
    float* gimean = tm     + N_SM;
    float* gibuf  = gimean + (size_t)Bq * Mm;
    float* gmbuf  = gibuf  + (size_t)Bq * NGg;
    float* skp    = gmbuf  + (size_t)Bq * Ss * NGg;       // split-K partials
    const size_t SKP_FLOATS = (size_t)8 * 512 * 1024;     // 4.19M floats (max use)
    float* bkv    = skp + SKP_FLOATS;                     // [2048] concat bias
    float* pconst = bkv + NGg;
    // bf16 constants
    ushort* ib16 = (ushort*)pconst;                       // [B*T][DIN]
    ushort* WpT  = ib16 + (size_t)Bq * Tt * DIN;          // [M][DIN]
    ushort* WkvT = WpT  + (size_t)Mm * DIN;               // [2M][M]: WkT then WvT
    ushort* cend = WkvT + (size_t)2 * Mm * Mm;
    // chunk region start (float*, 16B aligned)
    size_t const_u16 = (size_t)(cend - (ushort*)pconst);
    size_t const_floats = (size_t)(pconst - ws) + (const_u16 + 1) / 2;
    const_floats = (const_floats + 3) & ~(size_t)3;       // 16B align
    float* cstart = ws + const_floats;

    // per-chunk: kv bf16 (Bc*T*2M u16) + xb16 (Bc*T*M u16)
    int Bc = Bq;
    while (Bc > 1 &&
           (const_floats + (size_t)Bc * Tt * Mm * 3 / 2) * sizeof(float) > ws_size)
        Bc >>= 1;
    const size_t N_XC = (size_t)Bc * Tt * Mm;
    ushort* kvb16 = (ushort*)cstart;                      // [Bc*T][2M]
    ushort* xb16  = kvb16 + 2 * N_XC;                     // [Bc*T][M]

    const dim3 blk(256);

    // ---- precompute bf16 operands + concat bias ----
    conv_bf16<<<dim3((Bq * Tt * DIN) / 1024), blk, 0, stream>>>(inputs, ib16);
    transpose_to_bf16<<<dim3(Mm / 32, DIN / 32), blk, 0, stream>>>(Wp, WpT, DIN, Mm);
    transpose_to_bf16<<<dim3(Mm / 32, Mm / 32), blk, 0, stream>>>(Wk, WkvT, Mm, Mm);
    transpose_to_bf16<<<dim3(Mm / 32, Mm / 32), blk, 0, stream>>>(Wv, WkvT + (size_t)Mm * Mm, Mm, Mm);
    concat2<<<dim3(NGg / 256), blk, 0, stream>>>(bk, bv, bkv);

    // q = memory @ Wq + bq   (split-K=8)
    gemm_f32_sk<64,64,16,4,4,8><<<dim3(Mm/64, (Bq*Ss)/64, 8), blk, 0, stream>>>(
        memory, Mm, 0, Wq, Mm, 0, skp, Bq*Ss, Mm, Mm);
    sk_reduce<8,false><<<dim3((Bq*Ss*Mm)/1024), blk, 0, stream>>>(
        skp, bq, 0, qbuf, Mm, 0, (Bq*Ss*Mm)/4, Mm);

    // ---- chunked: x(bf16), kv(bf16), gi_reduce, attention ----
    for (int c0 = 0; c0 < Bq; c0 += Bc) {
        const int rows = Bc * Tt;

        // x_bf16 = bf16(inputs_c @ Wp + bp)   (reg-resident MFMA)
        gemm_8ph<1><<<dim3(Mm/256, rows/256), dim3(512), 131072, stream>>>(
            ib16 + (size_t)c0 * Tt * DIN, WpT, bp, xb16, Mm, DIN);

        // kv = bf16(x @ [Wk|Wv] + [bk|bv])    (reg-resident MFMA, N=2048)
        gemm_8ph<1><<<dim3((2*Mm)/256, rows/256), dim3(512), 131072, stream>>>(
            xb16, WkvT, bkv, kvb16, 2*Mm, Mm);

        // gi_mean_c = mean_t relu(rl_w * x)
        gi_reduce<<<dim3(Bc * (Mm/256)), blk, 0, stream>>>(
            xb16, rl_w, gimean + (size_t)c0 * Mm);

        // attention for this chunk
        attn_kernel<<<dim3(Bc * Hh), blk, 0, stream>>>(
            qbuf + (size_t)c0 * Ss * Mm, kvb16,
            attb + (size_t)c0 * Ss * Mm);
    }

    // mem1 = LN(memory + att)
    ln_add<<<dim3(Bq * Ss), blk, 0, stream>>>(memory, attb, g1, be1, mem1);

    // mlp1 = relu(mem1 @ Wm + bm)   (split-K=8)
    gemm_f32_sk<64,64,16,4,4,8><<<dim3(Mm/64, (Bq*Ss)/64, 8), blk, 0, stream>>>(
        mem1, Mm, 0, Wm, Mm, 0, skp, Bq*Ss, Mm, Mm);
    sk_reduce<8,true><<<dim3((Bq*Ss*Mm)/1024), blk, 0, stream>>>(
        skp, bm, 0, mlp1, Mm, 0, (Bq*Ss*Mm)/4, Mm);

    // mlp2 = relu(mlp1 @ Wm + bm)
    gemm_f32_sk<64,64,16,4,4,8><<<dim3(Mm/64, (Bq*Ss)/64, 8), blk, 0, stream>>>(
        mlp1, Mm, 0, Wm, Mm, 0, skp, Bq*Ss, Mm, Mm);
    sk_reduce<8,true><<<dim3((Bq*Ss*Mm)/1024), blk, 0, stream>>>(
        skp, bm, 0, mlp2, Mm, 0, (Bq*Ss*Mm)/4, Mm);

    // next = LN(mem1 + mlp2)
    ln_add<<<dim3(Bq * Ss), blk, 0, stream>>>(mem1, mlp2, g2, be2, nextm);

    // tm = tanh(memory)
    tanh_kernel<<<dim3((Bq*Ss*Mm)/256), blk, 0, stream>>>(memory, tm);

    // gm[:, s, :] = tm[:, s, :] @ gl_W[s] + gl_b[s]   (batch z=8, split-K=4)
    gemm_f32_sk<64,64,16,4,4,4><<<dim3(NGg/64, Bq/64, Ss*4), blk, 0, stream>>>(
        tm, Ss*Mm, (long long)Mm,
        gl_W, NGg, (long long)Mm * NGg,
        skp, Bq, NGg, Mm);
    sk_reduce<4,false><<<dim3((Ss*Bq*NGg)/1024), blk, 0, stream>>>(
        skp, gl_b, NGg, gmbuf, Ss*NGg, NGg, (Bq*NGg)/4, NGg);

    // gi = gi_mean @ rl_W + rl_b   (split-K=8)
    gemm_f32_sk<64,64,16,4,4,8><<<dim3(NGg/64, Bq/64, 8), blk, 0, stream>>>(
        gimean, Mm, 0, rl_W, NGg, 0, skp, Bq, NGg, Mm);
    sk_reduce<8,false><<<dim3((Bq*NGg)/1024), blk, 0, stream>>>(
        skp, rl_b, 0, gibuf, NGg, 0, (Bq*NGg)/4, NGg);

    // final gates + output
    combine_kernel<<<dim3((Bq*Ss*Mm)/256), blk, 0, stream>>>(
        gmbuf, gibuf, nextm, memory, ibp, fbp, out);
}